// Round 11
// baseline (1361.846 us; speedup 1.0000x reference)
//
#include <hip/hip_runtime.h>
#include <cstdint>

#define T_ 32
#define N_ 5000
#define E_ 80000
#define H_ 128
#define HD_ 512
#define C_ 10

typedef _Float16 f16;
typedef f16 f16x8 __attribute__((ext_vector_type(8)));
typedef f16 f16x4 __attribute__((ext_vector_type(4)));
typedef f16 f16x2 __attribute__((ext_vector_type(2)));
typedef float f32x4 __attribute__((ext_vector_type(4)));

#define LDA 136   // padded LDS leading dim in f16
#define NB_ 8     // CSR-build blocks per graph
#define EPS_ (E_ / NB_)  // 10000 edges per block
#define NBLK_ 313 // ceil(N_/16) node/row blocks per graph
#define GEMMB 768 // gemm grid: 96 blocks/XCD * 8
#define ZROW_ 320064  // zero-row index rel. to P16: (2*BIG + 8192 f16)/128

__device__ inline float fast_tanh(float x) {
    return 1.0f - 2.0f / (__expf(2.0f * x) + 1.0f);
}

__device__ inline f16x8 cvt8(float4 a, float4 b) {
    return (f16x8){(f16)a.x, (f16)a.y, (f16)a.z, (f16)a.w,
                   (f16)b.x, (f16)b.y, (f16)b.z, (f16)b.w};
}

// ---------------- CSR build, LDS-atomic (no global atomics) ----------------
__global__ __launch_bounds__(256) void k_count(const int* __restrict__ ei, int* __restrict__ part) {
    __shared__ int cnt[N_];
    int blk = blockIdx.x;
    int t = blk & 31, seg = blk >> 5;
    int tid = threadIdx.x;
    for (int i = tid; i < N_; i += 256) cnt[i] = 0;
    __syncthreads();
    const int* dst = ei + (size_t)t * 2 * E_ + E_ + seg * EPS_;
    for (int e = tid * 4; e < EPS_; e += 1024) {
        int4 d = *(const int4*)&dst[e];
        atomicAdd(&cnt[d.x], 1);
        atomicAdd(&cnt[d.y], 1);
        atomicAdd(&cnt[d.z], 1);
        atomicAdd(&cnt[d.w], 1);
    }
    __syncthreads();
    int* p = part + (t * NB_ + seg) * N_;
    for (int i = tid * 4; i < N_; i += 1024) *(int4*)&p[i] = *(const int4*)&cnt[i];
}

// ---------------- scan v2: coalesced degree/fixup phases, LDS-staged scan ----------------
// Also zeroes z (node-sum accumulator, filled by k_aggr_red atomics) and the
// dedicated zerorow (gather redirect target; z+4096 floats; never written again).
__global__ __launch_bounds__(256) void k_scan(int* __restrict__ part, int* __restrict__ ptr,
                                              float* __restrict__ dinv, float* __restrict__ z) {
    __shared__ int cnt[N_];      // degree, then start offset
    __shared__ int red[256];
    int t = blockIdx.x, tid = threadIdx.x;
    int base = t * N_;
    if (tid < 128) z[t * 128 + tid] = 0.0f;            // accumulator zero-init
    if (tid >= 128 && tid < 192) z[4096 + (tid - 128)] = 0.0f;  // zerorow (benign multi-block)
    int* pp = part + t * NB_ * N_;

    // Phase A: coalesced degree computation
    for (int i = tid; i < N_; i += 256) {
        int c = 0;
#pragma unroll
        for (int s = 0; s < NB_; ++s) c += pp[s * N_ + i];
        cnt[i] = c;
        dinv[base + i] = rsqrtf((float)(c + 1));  // +1 self-loop
    }
    __syncthreads();

    // Phase B: block scan over blocked 20-element runs (LDS source)
    int vals[20];
    int sum = 0;
#pragma unroll
    for (int j = 0; j < 20; ++j) {
        int i = tid * 20 + j;
        int c = (i < N_) ? cnt[i] : 0;
        vals[j] = sum;
        sum += c;
    }
    red[tid] = sum;
    __syncthreads();
    for (int off = 1; off < 256; off <<= 1) {
        int v = (tid >= off) ? red[tid - off] : 0;
        __syncthreads();
        red[tid] += v;
        __syncthreads();
    }
    int prev = (tid > 0) ? red[tid - 1] : 0;
#pragma unroll
    for (int j = 0; j < 20; ++j) {
        int i = tid * 20 + j;
        if (i < N_) cnt[i] = prev + vals[j];   // overwrite degree with start offset
    }
    __syncthreads();

    // Phase C: coalesced ptr write + per-segment running-offset fixup
    for (int i = tid; i < N_; i += 256) {
        int run = cnt[i];
        ptr[base + i] = run;
#pragma unroll
        for (int s = 0; s < NB_; ++s) {
            int c = pp[s * N_ + i];
            pp[s * N_ + i] = run;
            run += c;
        }
    }
}

__global__ __launch_bounds__(256) void k_scatter(const int* __restrict__ ei,
                                                 const int* __restrict__ part,
                                                 uint16_t* __restrict__ col) {
    __shared__ int cur[N_];
    int blk = blockIdx.x;
    int t = blk & 31, seg = blk >> 5;
    int tid = threadIdx.x;
    const int* off = part + (t * NB_ + seg) * N_;
    for (int i = tid * 4; i < N_; i += 1024) *(int4*)&cur[i] = *(const int4*)&off[i];
    __syncthreads();
    const int* src = ei + (size_t)t * 2 * E_ + seg * EPS_;
    const int* dst = src + E_;
    uint16_t* cl = col + (size_t)t * E_;
    for (int e = tid * 4; e < EPS_; e += 1024) {
        int4 s4 = *(const int4*)&src[e];
        int4 d4 = *(const int4*)&dst[e];
        cl[atomicAdd(&cur[d4.x], 1)] = (uint16_t)s4.x;
        cl[atomicAdd(&cur[d4.y], 1)] = (uint16_t)s4.y;
        cl[atomicAdd(&cur[d4.z], 1)] = (uint16_t)s4.z;
        cl[atomicAdd(&cur[d4.w], 1)] = (uint16_t)s4.w;
    }
}

// ---------------- weight prep: Wt[l][c][k] = (f16)W_l[k][c] ----------------
__global__ __launch_bounds__(256) void k_wprep(const float* __restrict__ W0,
                                               const float* __restrict__ W1,
                                               const float* __restrict__ W2,
                                               f16* __restrict__ Wt) {
    const float* W = (blockIdx.x == 0) ? W0 : (blockIdx.x == 1) ? W1 : W2;
    f16* dst = Wt + blockIdx.x * 16384;
    for (int idx = threadIdx.x; idx < 16384; idx += 256) {
        int c = idx >> 7, k = idx & 127;
        dst[idx] = (f16)W[k * 128 + c];
    }
}

// ---------------- MFMA GEMM v5: barrier-free streaming (measured keeper) ----------------
// K=128 fits one wave's MFMA fragments: no inter-wave A sharing. Stage Ws once ->
// ONE barrier -> waves grid-stride independent 16-row tasks; A direct global->reg;
// transpose via per-wave private LDS slab (lgkmcnt only); 1KB coalesced stores.
template <bool F32IN>
__global__ __launch_bounds__(256, 3) void k_gemm(const void* __restrict__ in_,
                                                 const f16* __restrict__ Wt,  // [c][k]
                                                 const float* __restrict__ dinv,
                                                 f16* __restrict__ g) {
    __shared__ f16 Ws[128 * LDA];
    __shared__ f16 slab[4][16 * LDA];
    int tid = threadIdx.x;
    {
        int c = tid >> 1, hf = tid & 1;
        const f16* src = Wt + c * 128 + hf * 64;
        f16* dst = Ws + c * LDA + hf * 64;
#pragma unroll
        for (int j = 0; j < 8; ++j) *(f16x8*)&dst[j * 8] = *(const f16x8*)&src[j * 8];
    }
    __syncthreads();   // the ONLY barrier; waves run free below

    int xc = blockIdx.x & 7;
    int jb = blockIdx.x >> 3;            // 0..95 per XCD
    int w = tid >> 6, lane = tid & 63;
    int m = lane & 15, q = lane >> 4;
    int co = q * 8;
    f16* sl = slab[w];
    int srow = lane >> 4;                // store row-within-quad
    int scol = (lane & 15) * 8;          // store col

    for (int task = jb * 4 + w; task < 4 * NBLK_; task += 384) {
        int gsel = task / NBLK_;
        int tile = task - gsel * NBLK_;
        int t = xc + (gsel << 3);
        int base = t * N_;
        int r0 = tile * 16;
        int rowA = r0 + m; if (rowA >= N_) rowA = N_ - 1;   // clamp (not stored)

        // A fragments: direct global -> registers
        f16x8 a0, a1, a2, a3;
        if (F32IN) {
            const float* src = (const float*)in_ + (((size_t)(base + rowA)) << 7) + co;
            float4 u0 = *(const float4*)&src[0];
            float4 u1 = *(const float4*)&src[4];
            float4 u2 = *(const float4*)&src[32];
            float4 u3 = *(const float4*)&src[36];
            float4 u4 = *(const float4*)&src[64];
            float4 u5 = *(const float4*)&src[68];
            float4 u6 = *(const float4*)&src[96];
            float4 u7 = *(const float4*)&src[100];
            a0 = cvt8(u0, u1); a1 = cvt8(u2, u3); a2 = cvt8(u4, u5); a3 = cvt8(u6, u7);
        } else {
            const f16* src = (const f16*)in_ + (((size_t)(base + rowA)) << 7) + co;
            a0 = *(const f16x8*)&src[0];
            a1 = *(const f16x8*)&src[32];
            a2 = *(const f16x8*)&src[64];
            a3 = *(const f16x8*)&src[96];
        }

        f32x4 acc[8];
#pragma unroll
        for (int n = 0; n < 8; ++n) acc[n] = (f32x4){0.f, 0.f, 0.f, 0.f};
#pragma unroll
        for (int n = 0; n < 8; ++n) {
            f16x8 bF = *(const f16x8*)&Ws[(n * 16 + m) * LDA + co];
            acc[n] = __builtin_amdgcn_mfma_f32_16x16x32_f16(a0, bF, acc[n], 0, 0, 0);
        }
#pragma unroll
        for (int n = 0; n < 8; ++n) {
            f16x8 bF = *(const f16x8*)&Ws[(n * 16 + m) * LDA + 32 + co];
            acc[n] = __builtin_amdgcn_mfma_f32_16x16x32_f16(a1, bF, acc[n], 0, 0, 0);
        }
#pragma unroll
        for (int n = 0; n < 8; ++n) {
            f16x8 bF = *(const f16x8*)&Ws[(n * 16 + m) * LDA + 64 + co];
            acc[n] = __builtin_amdgcn_mfma_f32_16x16x32_f16(a2, bF, acc[n], 0, 0, 0);
        }
#pragma unroll
        for (int n = 0; n < 8; ++n) {
            f16x8 bF = *(const f16x8*)&Ws[(n * 16 + m) * LDA + 96 + co];
            acc[n] = __builtin_amdgcn_mfma_f32_16x16x32_f16(a3, bF, acc[n], 0, 0, 0);
        }

        // epilogue: dinv scale -> per-wave slab (transpose) -> coalesced store
#pragma unroll
        for (int i = 0; i < 4; ++i) {
            int rr = q * 4 + i;
            int gr = r0 + rr; if (gr >= N_) gr = N_ - 1;
            float d = dinv[base + gr];
#pragma unroll
            for (int n = 0; n < 8; ++n)
                sl[rr * LDA + n * 16 + m] = (f16)(acc[n][i] * d);
        }
        asm volatile("s_waitcnt lgkmcnt(0)" ::: "memory");  // wave-internal write->read fence
#pragma unroll
        for (int j4 = 0; j4 < 4; ++j4) {
            int row = j4 * 4 + srow;
            f16x8 v = *(const f16x8*)&sl[row * LDA + scol];
            if (r0 + row < N_)
                *(f16x8*)&g[(((size_t)(base + r0 + row)) << 7) + scol] = v;  // 1KB/wave contiguous
        }
    }
}

// ---------------- CSR gather v4 (measured best; layers 1 & 2) ----------------
// (1) Graph-major per-XCD block order: XCD = blk&7; one graph's gather set
//     (~2.7MB) stays resident in the 4MB XCD L2 (FETCH 105 -> 23MB).
// (2) 8-aligned edge chunks: one dwordx4 col load per 8 edges (prefetched one
//     chunk ahead); out-of-range lanes redirected via ONE cndmask to the
//     DEDICATED zerorow (z+4096 floats; row ZROW_-5000t rel. to gg=P16;
//     zeroed by k_scan, never written afterwards). Adds unconditional.
__global__ __launch_bounds__(256) void k_aggr(const int* __restrict__ ptr,
                                              const uint16_t* __restrict__ col,
                                              const f16* __restrict__ g,
                                              const float* __restrict__ dinv,
                                              const float* __restrict__ b,
                                              f16* __restrict__ out) {
    int x = blockIdx.x & 7;
    int j = blockIdx.x >> 3;
    int gsel = j / NBLK_;
    int nb = j - gsel * NBLK_;
    int t = x + (gsel << 3);

    int w = threadIdx.x >> 6;
    int lane = threadIdx.x & 63;
    int q = lane >> 4, m = lane & 15;
    int n0 = nb * 16 + w * 4;    // wave's first node (4-aligned)
    if (n0 >= N_) return;        // tail waves (no barriers in this kernel)
    int base = t * N_;
    const f16* gg = g + (size_t)base * H_;
    const uint16_t* cl = col + (size_t)t * E_;
    int n = n0 + q;              // this 16-lane group's node
    unsigned moB = (unsigned)(m * 8);   // lane's 8-col slice (element offset)

    int4 p4 = *(const int4*)&ptr[base + n0];
    int pend = (n0 + 4 < N_) ? ptr[base + n0 + 4] : E_;
    int begin = (q == 0) ? p4.x : (q == 1) ? p4.y : (q == 2) ? p4.z : p4.w;
    int end   = (q == 0) ? p4.y : (q == 1) ? p4.z : (q == 2) ? p4.w : pend;

    float dn = dinv[base + n];
    float4 b4a = *(const float4*)&b[m * 8];
    float4 b4b = *(const float4*)&b[m * 8 + 4];

    int zidx = ZROW_ - 5000 * t;

    f16x8 a0 = *(const f16x8*)&gg[((unsigned)n << 7) + moB];  // self-loop row
    f16x8 a1 = {}, a2 = {}, a3 = {}, a4 = {}, a5 = {}, a6 = {}, a7 = {};

    int e0 = begin & ~7;
    int elast = (end - 1) & ~7;
    unsigned span = (unsigned)(end - begin);
    uint4 cc = *(const uint4*)&cl[e0];
    for (int e = e0; e < end; e += 8) {
        int en = e + 8;
        int epf = en < elast ? en : elast;
        uint4 cn = *(const uint4*)&cl[epf];
        unsigned eb = (unsigned)(e - begin);
        int i0 = (int)(cc.x & 0xFFFFu), i1 = (int)(cc.x >> 16);
        int i2 = (int)(cc.y & 0xFFFFu), i3 = (int)(cc.y >> 16);
        int i4 = (int)(cc.z & 0xFFFFu), i5 = (int)(cc.z >> 16);
        int i6 = (int)(cc.w & 0xFFFFu), i7 = (int)(cc.w >> 16);
        int s0 = (eb + 0 < span) ? i0 : zidx;
        int s1 = (eb + 1 < span) ? i1 : zidx;
        int s2 = (eb + 2 < span) ? i2 : zidx;
        int s3 = (eb + 3 < span) ? i3 : zidx;
        int s4 = (eb + 4 < span) ? i4 : zidx;
        int s5 = (eb + 5 < span) ? i5 : zidx;
        int s6 = (eb + 6 < span) ? i6 : zidx;
        int s7 = (eb + 7 < span) ? i7 : zidx;
        f16x8 v0 = *(const f16x8*)&gg[((unsigned)s0 << 7) + moB];
        f16x8 v1 = *(const f16x8*)&gg[((unsigned)s1 << 7) + moB];
        f16x8 v2 = *(const f16x8*)&gg[((unsigned)s2 << 7) + moB];
        f16x8 v3 = *(const f16x8*)&gg[((unsigned)s3 << 7) + moB];
        f16x8 v4 = *(const f16x8*)&gg[((unsigned)s4 << 7) + moB];
        f16x8 v5 = *(const f16x8*)&gg[((unsigned)s5 << 7) + moB];
        f16x8 v6 = *(const f16x8*)&gg[((unsigned)s6 << 7) + moB];
        f16x8 v7 = *(const f16x8*)&gg[((unsigned)s7 << 7) + moB];
        a0 += v0; a1 += v1; a2 += v2; a3 += v3;
        a4 += v4; a5 += v5; a6 += v6; a7 += v7;
        cc = cn;
    }
    a0 += a1; a2 += a3; a4 += a5; a6 += a7;
    a0 += a2; a4 += a6;
    a0 += a4;

    f16x8 o;
#pragma unroll
    for (int jj = 0; jj < 8; ++jj) {
        float bj = (jj < 4) ? ((const float*)&b4a)[jj] : ((const float*)&b4b)[jj - 4];
        o[jj] = (f16)fast_tanh(dn * (float)a0[jj] + bj);
    }
    *(f16x8*)&out[((size_t)base + n) * H_ + moB] = o;  // contiguous 1 KB wave store
}

// ---------------- CSR gather + fused node-sum (final layer) ----------------
// Same barrier-free gather as k_aggr; instead of the 40MB global store, the
// wave reduces its 4 nodes' tanh outputs in-register (16 shfl_xor, named
// scalars) and lanes q==0 atomicAdd the 128-col partial into z[t*128+..].
// 5.1M f32 atomics over 4096 addresses -- fire-and-forget, no barrier.
// Eliminates k_reduce (40MB read) and aggr3's 40MB write.
__global__ __launch_bounds__(256) void k_aggr_red(const int* __restrict__ ptr,
                                                  const uint16_t* __restrict__ col,
                                                  const f16* __restrict__ g,
                                                  const float* __restrict__ dinv,
                                                  const float* __restrict__ b,
                                                  float* __restrict__ z) {
    int x = blockIdx.x & 7;
    int j = blockIdx.x >> 3;
    int gsel = j / NBLK_;
    int nb = j - gsel * NBLK_;
    int t = x + (gsel << 3);

    int w = threadIdx.x >> 6;
    int lane = threadIdx.x & 63;
    int q = lane >> 4, m = lane & 15;
    int n0 = nb * 16 + w * 4;
    if (n0 >= N_) return;
    int base = t * N_;
    const f16* gg = g + (size_t)base * H_;
    const uint16_t* cl = col + (size_t)t * E_;
    int n = n0 + q;
    unsigned moB = (unsigned)(m * 8);

    int4 p4 = *(const int4*)&ptr[base + n0];
    int pend = (n0 + 4 < N_) ? ptr[base + n0 + 4] : E_;
    int begin = (q == 0) ? p4.x : (q == 1) ? p4.y : (q == 2) ? p4.z : p4.w;
    int end   = (q == 0) ? p4.y : (q == 1) ? p4.z : (q == 2) ? p4.w : pend;

    float dn = dinv[base + n];
    float4 b4a = *(const float4*)&b[m * 8];
    float4 b4b = *(const float4*)&b[m * 8 + 4];

    int zidx = ZROW_ - 5000 * t;

    f16x8 a0 = *(const f16x8*)&gg[((unsigned)n << 7) + moB];  // self-loop row
    f16x8 a1 = {}, a2 = {}, a3 = {}, a4 = {}, a5 = {}, a6 = {}, a7 = {};

    int e0 = begin & ~7;
    int elast = (end - 1) & ~7;
    unsigned span = (unsigned)(end - begin);
    uint4 cc = *(const uint4*)&cl[e0];
    for (int e = e0; e < end; e += 8) {
        int en = e + 8;
        int epf = en < elast ? en : elast;
        uint4 cn = *(const uint4*)&cl[epf];
        unsigned eb = (unsigned)(e - begin);
        int i0 = (int)(cc.x & 0xFFFFu), i1 = (int)(cc.x >> 16);
        int i2 = (int)(cc.y & 0xFFFFu), i3 = (int)(cc.y >> 16);
        int i4 = (int)(cc.z & 0xFFFFu), i5 = (int)(cc.z >> 16);
        int i6 = (int)(cc.w & 0xFFFFu), i7 = (int)(cc.w >> 16);
        int s0 = (eb + 0 < span) ? i0 : zidx;
        int s1 = (eb + 1 < span) ? i1 : zidx;
        int s2 = (eb + 2 < span) ? i2 : zidx;
        int s3 = (eb + 3 < span) ? i3 : zidx;
        int s4 = (eb + 4 < span) ? i4 : zidx;
        int s5 = (eb + 5 < span) ? i5 : zidx;
        int s6 = (eb + 6 < span) ? i6 : zidx;
        int s7 = (eb + 7 < span) ? i7 : zidx;
        f16x8 v0 = *(const f16x8*)&gg[((unsigned)s0 << 7) + moB];
        f16x8 v1 = *(const f16x8*)&gg[((unsigned)s1 << 7) + moB];
        f16x8 v2 = *(const f16x8*)&gg[((unsigned)s2 << 7) + moB];
        f16x8 v3 = *(const f16x8*)&gg[((unsigned)s3 << 7) + moB];
        f16x8 v4 = *(const f16x8*)&gg[((unsigned)s4 << 7) + moB];
        f16x8 v5 = *(const f16x8*)&gg[((unsigned)s5 << 7) + moB];
        f16x8 v6 = *(const f16x8*)&gg[((unsigned)s6 << 7) + moB];
        f16x8 v7 = *(const f16x8*)&gg[((unsigned)s7 << 7) + moB];
        a0 += v0; a1 += v1; a2 += v2; a3 += v3;
        a4 += v4; a5 += v5; a6 += v6; a7 += v7;
        cc = cn;
    }
    a0 += a1; a2 += a3; a4 += a5; a6 += a7;
    a0 += a2; a4 += a6;
    a0 += a4;

    // tanh outputs (f16-rounded to match stored-value semantics), as f32 scalars
    float s0_, s1_, s2_, s3_, s4_, s5_, s6_, s7_;
    {
        float bj0 = ((const float*)&b4a)[0], bj1 = ((const float*)&b4a)[1];
        float bj2 = ((const float*)&b4a)[2], bj3 = ((const float*)&b4a)[3];
        float bj4 = ((const float*)&b4b)[0], bj5 = ((const float*)&b4b)[1];
        float bj6 = ((const float*)&b4b)[2], bj7 = ((const float*)&b4b)[3];
        s0_ = (float)(f16)fast_tanh(dn * (float)a0[0] + bj0);
        s1_ = (float)(f16)fast_tanh(dn * (float)a0[1] + bj1);
        s2_ = (float)(f16)fast_tanh(dn * (float)a0[2] + bj2);
        s3_ = (float)(f16)fast_tanh(dn * (float)a0[3] + bj3);
        s4_ = (float)(f16)fast_tanh(dn * (float)a0[4] + bj4);
        s5_ = (float)(f16)fast_tanh(dn * (float)a0[5] + bj5);
        s6_ = (float)(f16)fast_tanh(dn * (float)a0[6] + bj6);
        s7_ = (float)(f16)fast_tanh(dn * (float)a0[7] + bj7);
    }
    // sum across the wave's 4 nodes (lanes differ only in q for fixed m)
    s0_ += __shfl_xor(s0_, 16, 64); s0_ += __shfl_xor(s0_, 32, 64);
    s1_ += __shfl_xor(s1_, 16, 64); s1_ += __shfl_xor(s1_, 32, 64);
    s2_ += __shfl_xor(s2_, 16, 64); s2_ += __shfl_xor(s2_, 32, 64);
    s3_ += __shfl_xor(s3_, 16, 64); s3_ += __shfl_xor(s3_, 32, 64);
    s4_ += __shfl_xor(s4_, 16, 64); s4_ += __shfl_xor(s4_, 32, 64);
    s5_ += __shfl_xor(s5_, 16, 64); s5_ += __shfl_xor(s5_, 32, 64);
    s6_ += __shfl_xor(s6_, 16, 64); s6_ += __shfl_xor(s6_, 32, 64);
    s7_ += __shfl_xor(s7_, 16, 64); s7_ += __shfl_xor(s7_, 32, 64);
    if (q == 0) {
        float* zp = z + t * 128 + m * 8;
        atomicAdd(&zp[0], s0_); atomicAdd(&zp[1], s1_);
        atomicAdd(&zp[2], s2_); atomicAdd(&zp[3], s3_);
        atomicAdd(&zp[4], s4_); atomicAdd(&zp[5], s5_);
        atomicAdd(&zp[6], s6_); atomicAdd(&zp[7], s7_);
    }
}

// ---------------- head stage 1: q,k,v ----------------
__global__ __launch_bounds__(128) void k_qkv(const float* __restrict__ z,
                                             const float* __restrict__ Wq, const float* __restrict__ bq,
                                             const float* __restrict__ Wk, const float* __restrict__ bk,
                                             const float* __restrict__ Wv, const float* __restrict__ bv,
                                             float* __restrict__ q, float* __restrict__ k,
                                             float* __restrict__ v) {
    int t = blockIdx.x, c = threadIdx.x;
    __shared__ float zs[128];
    zs[c] = z[t * 128 + c];
    __syncthreads();
    float aq = bq[c], ak = bk[c], av = bv[c];
    for (int kk = 0; kk < 128; ++kk) {
        float zv = zs[kk];
        aq += zv * Wq[(kk << 7) + c];
        ak += zv * Wk[(kk << 7) + c];
        av += zv * Wv[(kk << 7) + c];
    }
    q[t * 128 + c] = aq;
    k[t * 128 + c] = ak;
    v[t * 128 + c] = av;
}

// ---------------- head stage 2 ----------------
__global__ __launch_bounds__(256) void k_attnmid(
    const float* __restrict__ q, const float* __restrict__ k, const float* __restrict__ v,
    const float* __restrict__ Wo, const float* __restrict__ bo,
    const float* __restrict__ g2, const float* __restrict__ beta2,
    const float* __restrict__ Wm1, const float* __restrict__ bm1,
    const float* __restrict__ Wm2, const float* __restrict__ bm2,
    float* __restrict__ xr) {
    int t = blockIdx.x, tid = threadIdx.x;
    __shared__ float Ks[32 * 128], Vs[32 * 128];
    __shared__ float qs[128], sc[8 * 32], xa[128], hid[512], ys[128];
    __shared__ float redA[128], redB[128];

    for (int i = tid; i < 32 * 128; i += 256) { Ks[i] = k[i]; Vs[i] = v[i]; }
    if (tid < 128) qs[tid] = q[t * 128 + tid];
    __syncthreads();

    {
        int h = tid >> 5, s = tid & 31;
        float d = 0.0f;
#pragma unroll
        for (int kk = 0; kk < 16; ++kk)
            d += qs[(h << 4) + kk] * Ks[(s << 7) + (h << 4) + kk];
        sc[tid] = d * 0.25f;
    }
    __syncthreads();
    if (tid < 8) {
        float m = -1e30f;
        for (int s = 0; s < 32; ++s) m = fmaxf(m, sc[(tid << 5) + s]);
        float l = 0.0f;
        for (int s = 0; s < 32; ++s) { float e = __expf(sc[(tid << 5) + s] - m); sc[(tid << 5) + s] = e; l += e; }
        float inv = 1.0f / l;
        for (int s = 0; s < 32; ++s) sc[(tid << 5) + s] *= inv;
    }
    __syncthreads();
    if (tid < 128) {
        int h = tid >> 4;
        float o = 0.0f;
        for (int s = 0; s < 32; ++s) o += sc[(h << 5) + s] * Vs[(s << 7) + tid];
        qs[tid] = o;
    }
    __syncthreads();
    if (tid < 128) {
        float a = bo[tid];
        for (int kk = 0; kk < 128; ++kk) a += qs[kk] * Wo[(kk << 7) + tid];
        xa[tid] = a;
    }
    __syncthreads();
    for (int j = tid; j < 512; j += 256) {
        float a = bm1[j];
        for (int kk = 0; kk < 128; ++kk) a += xa[kk] * Wm1[(kk << 9) + j];
        hid[j] = fmaxf(a, 0.0f);
    }
    __syncthreads();
    if (tid < 128) {
        float a = bm2[tid];
        for (int j = 0; j < 512; ++j) a += hid[j] * Wm2[(j << 7) + tid];
        ys[tid] = xa[tid] + a;
    }
    __syncthreads();
    if (tid < 128) { redA[tid] = ys[tid]; redB[tid] = ys[tid] * ys[tid]; }
    __syncthreads();
    for (int off = 64; off > 0; off >>= 1) {
        if (tid < off) { redA[tid] += redA[tid + off]; redB[tid] += redB[tid + off]; }
        __syncthreads();
    }
    float mu = redA[0] * (1.0f / 128.0f);
    float var = redB[0] * (1.0f / 128.0f) - mu * mu;
    float rs = rsqrtf(var + 1e-5f);
    if (tid < 128) {
        float yv = (ys[tid] - mu) * rs * g2[tid] + beta2[tid];
        xr[t * 128 + tid] = fmaxf(yv, 0.0f);
    }
}

// ---------------- head stage 3 ----------------
__global__ __launch_bounds__(128) void k_final(const float* __restrict__ xr,
                                               const float* __restrict__ Wl,
                                               const float* __restrict__ bl,
                                               float* __restrict__ out) {
    int tid = threadIdx.x;
    __shared__ float pooled[128];
    float s = 0.0f;
    for (int t = 0; t < 32; ++t) s += xr[t * 128 + tid];
    pooled[tid] = s;
    __syncthreads();
    if (tid < C_) {
        float a = bl[tid];
        for (int kk = 0; kk < 128; ++kk) a += pooled[kk] * Wl[kk * C_ + tid];
        out[tid] = a;
    }
}

extern "C" void kernel_launch(void* const* d_in, const int* in_sizes, int n_in,
                              void* d_out, int out_size, void* d_ws, size_t ws_size,
                              hipStream_t stream) {
    const float* x  = (const float*)d_in[0];
    const int*   ei = (const int*)d_in[1];
    const float* W0 = (const float*)d_in[2];  const float* b0 = (const float*)d_in[3];
    const float* W1 = (const float*)d_in[4];  const float* b1 = (const float*)d_in[5];
    const float* W2 = (const float*)d_in[6];  const float* b2 = (const float*)d_in[7];
    const float* Wq = (const float*)d_in[8];  const float* bq = (const float*)d_in[9];
    const float* Wk = (const float*)d_in[10]; const float* bk = (const float*)d_in[11];
    const float* Wv = (const float*)d_in[12]; const float* bv = (const float*)d_in[13];
    const float* Wo = (const float*)d_in[14]; const float* bo = (const float*)d_in[15];
    const float* g2 = (const float*)d_in[16]; const float* beta2 = (const float*)d_in[17];
    const float* Wm1 = (const float*)d_in[18]; const float* bm1 = (const float*)d_in[19];
    const float* Wm2 = (const float*)d_in[20]; const float* bm2 = (const float*)d_in[21];
    const float* Wl = (const float*)d_in[22]; const float* bl = (const float*)d_in[23];
    float* outp = (float*)d_out;

    const size_t BIG = (size_t)T_ * N_ * H_;
    char* ws = (char*)d_ws;
    float*    dinv = (float*)(ws);
    int*      ptr  = (int*)(ws + 640000);
    uint16_t* col  = (uint16_t*)(ws + 1280000);
    f16*      Wt   = (f16*)(ws + 6400000);
    f16*      P16  = (f16*)(ws + 6498304);
    f16*      Q16  = P16 + BIG;
    float*    z    = (float*)(Q16 + BIG);   // [0..4095] accum; [4096..4159] zerorow (row ZROW_ rel P16)
    float*    zq   = z + 4096 + 64;
    float*    zk   = zq + 4096;
    float*    zv   = zk + 4096;
    float*    xr   = zv + 4096;
    int*      part = (int*)P16;   // CSR partials alias P16 (used only before first gemm)

    k_wprep<<<3, 256, 0, stream>>>(W0, W1, W2, Wt);
    k_count<<<NB_ * 32, 256, 0, stream>>>(ei, part);
    k_scan<<<T_, 256, 0, stream>>>(part, ptr, dinv, z);
    k_scatter<<<NB_ * 32, 256, 0, stream>>>(ei, part, col);

    const int AGGR_BLOCKS = NBLK_ * 32;   // 16 nodes/block, 4 nodes/wave
    k_gemm<true><<<GEMMB, 256, 0, stream>>>(x, Wt, dinv, P16);
    k_aggr<<<AGGR_BLOCKS, 256, 0, stream>>>(ptr, col, P16, dinv, b0, Q16);
    k_gemm<false><<<GEMMB, 256, 0, stream>>>(Q16, Wt + 16384, dinv, P16);
    k_aggr<<<AGGR_BLOCKS, 256, 0, stream>>>(ptr, col, P16, dinv, b1, Q16);
    k_gemm<false><<<GEMMB, 256, 0, stream>>>(Q16, Wt + 32768, dinv, P16);
    // final layer: gather + fused node-sum straight into z (no 40MB store, no k_reduce)
    k_aggr_red<<<AGGR_BLOCKS, 256, 0, stream>>>(ptr, col, P16, dinv, b2, z);

    k_qkv<<<T_, 128, 0, stream>>>(z, Wq, bq, Wk, bk, Wv, bv, zq, zk, zv);
    k_attnmid<<<T_, 256, 0, stream>>>(zq, zk, zv, Wo, bo, g2, beta2,
                                      Wm1, bm1, Wm2, bm2, xr);
    k_final<<<1, 128, 0, stream>>>(xr, Wl, bl, outp);
}

// Round 12
// 497.642 us; speedup vs baseline: 2.7366x; 2.7366x over previous
//
#include <hip/hip_runtime.h>
#include <cstdint>

#define T_ 32
#define N_ 5000
#define E_ 80000
#define H_ 128
#define HD_ 512
#define C_ 10

typedef _Float16 f16;
typedef f16 f16x8 __attribute__((ext_vector_type(8)));
typedef f16 f16x4 __attribute__((ext_vector_type(4)));
typedef f16 f16x2 __attribute__((ext_vector_type(2)));
typedef float f32x4 __attribute__((ext_vector_type(4)));

#define LDA 136   // padded LDS leading dim in f16
#define NB_ 8     // CSR-build blocks per graph
#define EPS_ (E_ / NB_)  // 10000 edges per block
#define NBLK_ 313 // ceil(N_/16) 16-row blocks per graph (gemm tasks)
#define NB64_ 79  // ceil(N_/64) 64-node blocks per graph (aggr)
#define GEMMB 768 // gemm grid: 96 blocks/XCD * 8
#define ZROW_ 320064  // zero-row index rel. to P16: (2*BIG + 8192 f16)/128

__device__ inline float fast_tanh(float x) {
    return 1.0f - 2.0f / (__expf(2.0f * x) + 1.0f);
}

__device__ inline f16x8 cvt8(float4 a, float4 b) {
    return (f16x8){(f16)a.x, (f16)a.y, (f16)a.z, (f16)a.w,
                   (f16)b.x, (f16)b.y, (f16)b.z, (f16)b.w};
}

// ---------------- CSR build, LDS-atomic (no global atomics) ----------------
__global__ __launch_bounds__(256) void k_count(const int* __restrict__ ei, int* __restrict__ part) {
    __shared__ int cnt[N_];
    int blk = blockIdx.x;
    int t = blk & 31, seg = blk >> 5;
    int tid = threadIdx.x;
    for (int i = tid; i < N_; i += 256) cnt[i] = 0;
    __syncthreads();
    const int* dst = ei + (size_t)t * 2 * E_ + E_ + seg * EPS_;
    for (int e = tid * 4; e < EPS_; e += 1024) {
        int4 d = *(const int4*)&dst[e];
        atomicAdd(&cnt[d.x], 1);
        atomicAdd(&cnt[d.y], 1);
        atomicAdd(&cnt[d.z], 1);
        atomicAdd(&cnt[d.w], 1);
    }
    __syncthreads();
    int* p = part + (t * NB_ + seg) * N_;
    for (int i = tid * 4; i < N_; i += 1024) *(int4*)&p[i] = *(const int4*)&cnt[i];
}

// ---------------- scan v2: coalesced degree/fixup phases, LDS-staged scan ----------------
// Also zeroes z (node-sum accumulator for k_reduce) and the dedicated zerorow
// (gather redirect target; z+4096 floats; never written afterwards).
__global__ __launch_bounds__(256) void k_scan(int* __restrict__ part, int* __restrict__ ptr,
                                              float* __restrict__ dinv, float* __restrict__ z) {
    __shared__ int cnt[N_];      // degree, then start offset
    __shared__ int red[256];
    int t = blockIdx.x, tid = threadIdx.x;
    int base = t * N_;
    if (tid < 128) z[t * 128 + tid] = 0.0f;            // accumulator zero-init
    if (tid >= 128 && tid < 192) z[4096 + (tid - 128)] = 0.0f;  // zerorow (benign multi-block)
    int* pp = part + t * NB_ * N_;

    // Phase A: coalesced degree computation
    for (int i = tid; i < N_; i += 256) {
        int c = 0;
#pragma unroll
        for (int s = 0; s < NB_; ++s) c += pp[s * N_ + i];
        cnt[i] = c;
        dinv[base + i] = rsqrtf((float)(c + 1));  // +1 self-loop
    }
    __syncthreads();

    // Phase B: block scan over blocked 20-element runs (LDS source)
    int vals[20];
    int sum = 0;
#pragma unroll
    for (int j = 0; j < 20; ++j) {
        int i = tid * 20 + j;
        int c = (i < N_) ? cnt[i] : 0;
        vals[j] = sum;
        sum += c;
    }
    red[tid] = sum;
    __syncthreads();
    for (int off = 1; off < 256; off <<= 1) {
        int v = (tid >= off) ? red[tid - off] : 0;
        __syncthreads();
        red[tid] += v;
        __syncthreads();
    }
    int prev = (tid > 0) ? red[tid - 1] : 0;
#pragma unroll
    for (int j = 0; j < 20; ++j) {
        int i = tid * 20 + j;
        if (i < N_) cnt[i] = prev + vals[j];   // overwrite degree with start offset
    }
    __syncthreads();

    // Phase C: coalesced ptr write + per-segment running-offset fixup
    for (int i = tid; i < N_; i += 256) {
        int run = cnt[i];
        ptr[base + i] = run;
#pragma unroll
        for (int s = 0; s < NB_; ++s) {
            int c = pp[s * N_ + i];
            pp[s * N_ + i] = run;
            run += c;
        }
    }
}

__global__ __launch_bounds__(256) void k_scatter(const int* __restrict__ ei,
                                                 const int* __restrict__ part,
                                                 uint16_t* __restrict__ col) {
    __shared__ int cur[N_];
    int blk = blockIdx.x;
    int t = blk & 31, seg = blk >> 5;
    int tid = threadIdx.x;
    const int* off = part + (t * NB_ + seg) * N_;
    for (int i = tid * 4; i < N_; i += 1024) *(int4*)&cur[i] = *(const int4*)&off[i];
    __syncthreads();
    const int* src = ei + (size_t)t * 2 * E_ + seg * EPS_;
    const int* dst = src + E_;
    uint16_t* cl = col + (size_t)t * E_;
    for (int e = tid * 4; e < EPS_; e += 1024) {
        int4 s4 = *(const int4*)&src[e];
        int4 d4 = *(const int4*)&dst[e];
        cl[atomicAdd(&cur[d4.x], 1)] = (uint16_t)s4.x;
        cl[atomicAdd(&cur[d4.y], 1)] = (uint16_t)s4.y;
        cl[atomicAdd(&cur[d4.z], 1)] = (uint16_t)s4.z;
        cl[atomicAdd(&cur[d4.w], 1)] = (uint16_t)s4.w;
    }
}

// ---------------- weight prep: Wt[l][c][k] = (f16)W_l[k][c] ----------------
__global__ __launch_bounds__(256) void k_wprep(const float* __restrict__ W0,
                                               const float* __restrict__ W1,
                                               const float* __restrict__ W2,
                                               f16* __restrict__ Wt) {
    const float* W = (blockIdx.x == 0) ? W0 : (blockIdx.x == 1) ? W1 : W2;
    f16* dst = Wt + blockIdx.x * 16384;
    for (int idx = threadIdx.x; idx < 16384; idx += 256) {
        int c = idx >> 7, k = idx & 127;
        dst[idx] = (f16)W[k * 128 + c];
    }
}

// ---------------- MFMA GEMM v5: barrier-free streaming (measured keeper) ----------------
// K=128 fits one wave's MFMA fragments: no inter-wave A sharing. Stage Ws once ->
// ONE barrier -> waves grid-stride independent 16-row tasks; A direct global->reg;
// transpose via per-wave private LDS slab (lgkmcnt only); 1KB coalesced stores.
template <bool F32IN>
__global__ __launch_bounds__(256, 3) void k_gemm(const void* __restrict__ in_,
                                                 const f16* __restrict__ Wt,  // [c][k]
                                                 const float* __restrict__ dinv,
                                                 f16* __restrict__ g) {
    __shared__ f16 Ws[128 * LDA];
    __shared__ f16 slab[4][16 * LDA];
    int tid = threadIdx.x;
    {
        int c = tid >> 1, hf = tid & 1;
        const f16* src = Wt + c * 128 + hf * 64;
        f16* dst = Ws + c * LDA + hf * 64;
#pragma unroll
        for (int j = 0; j < 8; ++j) *(f16x8*)&dst[j * 8] = *(const f16x8*)&src[j * 8];
    }
    __syncthreads();   // the ONLY barrier; waves run free below

    int xc = blockIdx.x & 7;
    int jb = blockIdx.x >> 3;            // 0..95 per XCD
    int w = tid >> 6, lane = tid & 63;
    int m = lane & 15, q = lane >> 4;
    int co = q * 8;
    f16* sl = slab[w];
    int srow = lane >> 4;                // store row-within-quad
    int scol = (lane & 15) * 8;          // store col

    for (int task = jb * 4 + w; task < 4 * NBLK_; task += 384) {
        int gsel = task / NBLK_;
        int tile = task - gsel * NBLK_;
        int t = xc + (gsel << 3);
        int base = t * N_;
        int r0 = tile * 16;
        int rowA = r0 + m; if (rowA >= N_) rowA = N_ - 1;   // clamp (not stored)

        // A fragments: direct global -> registers
        f16x8 a0, a1, a2, a3;
        if (F32IN) {
            const float* src = (const float*)in_ + (((size_t)(base + rowA)) << 7) + co;
            float4 u0 = *(const float4*)&src[0];
            float4 u1 = *(const float4*)&src[4];
            float4 u2 = *(const float4*)&src[32];
            float4 u3 = *(const float4*)&src[36];
            float4 u4 = *(const float4*)&src[64];
            float4 u5 = *(const float4*)&src[68];
            float4 u6 = *(const float4*)&src[96];
            float4 u7 = *(const float4*)&src[100];
            a0 = cvt8(u0, u1); a1 = cvt8(u2, u3); a2 = cvt8(u4, u5); a3 = cvt8(u6, u7);
        } else {
            const f16* src = (const f16*)in_ + (((size_t)(base + rowA)) << 7) + co;
            a0 = *(const f16x8*)&src[0];
            a1 = *(const f16x8*)&src[32];
            a2 = *(const f16x8*)&src[64];
            a3 = *(const f16x8*)&src[96];
        }

        f32x4 acc[8];
#pragma unroll
        for (int n = 0; n < 8; ++n) acc[n] = (f32x4){0.f, 0.f, 0.f, 0.f};
#pragma unroll
        for (int n = 0; n < 8; ++n) {
            f16x8 bF = *(const f16x8*)&Ws[(n * 16 + m) * LDA + co];
            acc[n] = __builtin_amdgcn_mfma_f32_16x16x32_f16(a0, bF, acc[n], 0, 0, 0);
        }
#pragma unroll
        for (int n = 0; n < 8; ++n) {
            f16x8 bF = *(const f16x8*)&Ws[(n * 16 + m) * LDA + 32 + co];
            acc[n] = __builtin_amdgcn_mfma_f32_16x16x32_f16(a1, bF, acc[n], 0, 0, 0);
        }
#pragma unroll
        for (int n = 0; n < 8; ++n) {
            f16x8 bF = *(const f16x8*)&Ws[(n * 16 + m) * LDA + 64 + co];
            acc[n] = __builtin_amdgcn_mfma_f32_16x16x32_f16(a2, bF, acc[n], 0, 0, 0);
        }
#pragma unroll
        for (int n = 0; n < 8; ++n) {
            f16x8 bF = *(const f16x8*)&Ws[(n * 16 + m) * LDA + 96 + co];
            acc[n] = __builtin_amdgcn_mfma_f32_16x16x32_f16(a3, bF, acc[n], 0, 0, 0);
        }

        // epilogue: dinv scale -> per-wave slab (transpose) -> coalesced store
#pragma unroll
        for (int i = 0; i < 4; ++i) {
            int rr = q * 4 + i;
            int gr = r0 + rr; if (gr >= N_) gr = N_ - 1;
            float d = dinv[base + gr];
#pragma unroll
            for (int n = 0; n < 8; ++n)
                sl[rr * LDA + n * 16 + m] = (f16)(acc[n][i] * d);
        }
        asm volatile("s_waitcnt lgkmcnt(0)" ::: "memory");  // wave-internal write->read fence
#pragma unroll
        for (int j4 = 0; j4 < 4; ++j4) {
            int row = j4 * 4 + srow;
            f16x8 v = *(const f16x8*)&sl[row * LDA + scol];
            if (r0 + row < N_)
                *(f16x8*)&g[(((size_t)(base + r0 + row)) << 7) + scol] = v;  // 1KB/wave contiguous
        }
    }
}

// ---------------- CSR gather v7: v4 body, 64 nodes/block (4 quads per wave) ----------------
// v4 @56us showed Occupancy 42% at VGPR=44/LDS=0: the limiter was BLOCK
// GRANULARITY (10016 x ~5us blocks outrun the CP's in-flight block supply),
// not a resource. v7: each block covers 64 consecutive nodes; each wave runs
// 4 sequential node-quads (same barrier-free v4 gather body per quad; later
// quads' ptr/col loads overlap earlier quads' drains). 2528 blocks x ~20us.
// [v11 post-mortem: atomic-reduce fusion catastrophically serialized (936us,
//  5M atomics / 4096 addrs); k_reduce restored. Two-bank pipelining also
//  failed twice (regalloc collapse) -- the gather loop itself stays v4.]
// Out-of-range lanes redirect via ONE cndmask to the dedicated zerorow
// (z+4096 floats; row ZROW_-5000t rel. to gg=P16; zeroed by k_scan).
__global__ __launch_bounds__(256) void k_aggr(const int* __restrict__ ptr,
                                              const uint16_t* __restrict__ col,
                                              const f16* __restrict__ g,
                                              const float* __restrict__ dinv,
                                              const float* __restrict__ b,
                                              f16* __restrict__ out) {
    int x = blockIdx.x & 7;
    int j = blockIdx.x >> 3;
    int gsel = j / NB64_;
    int nb64 = j - gsel * NB64_;
    int t = x + (gsel << 3);

    int w = threadIdx.x >> 6;
    int lane = threadIdx.x & 63;
    int q = lane >> 4, m = lane & 15;
    int base = t * N_;
    const f16* gg = g + (size_t)base * H_;
    const uint16_t* cl = col + (size_t)t * E_;
    unsigned moB = (unsigned)(m * 8);   // lane's 8-col slice (element offset)
    int zidx = ZROW_ - 5000 * t;
    float4 b4a = *(const float4*)&b[m * 8];      // hoisted across quads
    float4 b4b = *(const float4*)&b[m * 8 + 4];

#pragma unroll 1
    for (int kq = 0; kq < 4; ++kq) {
        int n0 = nb64 * 64 + kq * 16 + w * 4;    // this quad's first node (4-aligned)
        if (n0 >= N_) break;                      // n0 increases with kq; no barriers
        int n = n0 + q;

        int4 p4 = *(const int4*)&ptr[base + n0];
        int pend = (n0 + 4 < N_) ? ptr[base + n0 + 4] : E_;
        int begin = (q == 0) ? p4.x : (q == 1) ? p4.y : (q == 2) ? p4.z : p4.w;
        int end   = (q == 0) ? p4.y : (q == 1) ? p4.z : (q == 2) ? p4.w : pend;

        float dn = dinv[base + n];

        f16x8 a0 = *(const f16x8*)&gg[((unsigned)n << 7) + moB];  // self-loop row
        f16x8 a1 = {}, a2 = {}, a3 = {}, a4 = {}, a5 = {}, a6 = {}, a7 = {};

        int e0 = begin & ~7;
        int elast = (end - 1) & ~7;
        unsigned span = (unsigned)(end - begin);
        uint4 cc = *(const uint4*)&cl[e0];
        for (int e = e0; e < end; e += 8) {
            int en = e + 8;
            int epf = en < elast ? en : elast;
            uint4 cn = *(const uint4*)&cl[epf];   // prefetch next chunk's cols
            unsigned eb = (unsigned)(e - begin);  // wraps on first chunk; cmp trick ok
            int i0 = (int)(cc.x & 0xFFFFu), i1 = (int)(cc.x >> 16);
            int i2 = (int)(cc.y & 0xFFFFu), i3 = (int)(cc.y >> 16);
            int i4 = (int)(cc.z & 0xFFFFu), i5 = (int)(cc.z >> 16);
            int i6 = (int)(cc.w & 0xFFFFu), i7 = (int)(cc.w >> 16);
            int s0 = (eb + 0 < span) ? i0 : zidx;
            int s1 = (eb + 1 < span) ? i1 : zidx;
            int s2 = (eb + 2 < span) ? i2 : zidx;
            int s3 = (eb + 3 < span) ? i3 : zidx;
            int s4 = (eb + 4 < span) ? i4 : zidx;
            int s5 = (eb + 5 < span) ? i5 : zidx;
            int s6 = (eb + 6 < span) ? i6 : zidx;
            int s7 = (eb + 7 < span) ? i7 : zidx;
            f16x8 v0 = *(const f16x8*)&gg[((unsigned)s0 << 7) + moB];
            f16x8 v1 = *(const f16x8*)&gg[((unsigned)s1 << 7) + moB];
            f16x8 v2 = *(const f16x8*)&gg[((unsigned)s2 << 7) + moB];
            f16x8 v3 = *(const f16x8*)&gg[((unsigned)s3 << 7) + moB];
            f16x8 v4 = *(const f16x8*)&gg[((unsigned)s4 << 7) + moB];
            f16x8 v5 = *(const f16x8*)&gg[((unsigned)s5 << 7) + moB];
            f16x8 v6 = *(const f16x8*)&gg[((unsigned)s6 << 7) + moB];
            f16x8 v7 = *(const f16x8*)&gg[((unsigned)s7 << 7) + moB];
            a0 += v0; a1 += v1; a2 += v2; a3 += v3;
            a4 += v4; a5 += v5; a6 += v6; a7 += v7;
            cc = cn;
        }
        a0 += a1; a2 += a3; a4 += a5; a6 += a7;
        a0 += a2; a4 += a6;
        a0 += a4;

        f16x8 o;
#pragma unroll
        for (int jj = 0; jj < 8; ++jj) {
            float bj = (jj < 4) ? ((const float*)&b4a)[jj] : ((const float*)&b4b)[jj - 4];
            o[jj] = (f16)fast_tanh(dn * (float)a0[jj] + bj);
        }
        *(f16x8*)&out[((size_t)base + n) * H_ + moB] = o;  // contiguous 1 KB wave store
    }
}

// ---------------- node-sum: z[t][c] = sum_n h[t][n][c] ----------------
__global__ __launch_bounds__(256) void k_reduce(const f16* __restrict__ h, float* __restrict__ z) {
    int t = blockIdx.x, seg = blockIdx.y;
    int tid = threadIdx.x;
    int rg = tid >> 5;
    int c = (tid & 31) * 4;
    const f16* p = h + (size_t)t * N_ * H_;
    float4 acc = make_float4(0.f, 0.f, 0.f, 0.f);
    int n0 = seg * 500;
    for (int n = n0 + rg; n < n0 + 500; n += 8) {
        f16x4 v = *(const f16x4*)&p[(size_t)n * H_ + c];
        acc.x += (float)v[0]; acc.y += (float)v[1]; acc.z += (float)v[2]; acc.w += (float)v[3];
    }
    __shared__ float4 part[256];
    part[tid] = acc;
    __syncthreads();
    if (rg == 0) {
        float4 s = part[tid];
#pragma unroll
        for (int j = 1; j < 8; ++j) {
            float4 v = part[(j << 5) + tid];
            s.x += v.x; s.y += v.y; s.z += v.z; s.w += v.w;
        }
        atomicAdd(&z[t * H_ + c + 0], s.x);
        atomicAdd(&z[t * H_ + c + 1], s.y);
        atomicAdd(&z[t * H_ + c + 2], s.z);
        atomicAdd(&z[t * H_ + c + 3], s.w);
    }
}

// ---------------- head stage 1: q,k,v ----------------
__global__ __launch_bounds__(128) void k_qkv(const float* __restrict__ z,
                                             const float* __restrict__ Wq, const float* __restrict__ bq,
                                             const float* __restrict__ Wk, const float* __restrict__ bk,
                                             const float* __restrict__ Wv, const float* __restrict__ bv,
                                             float* __restrict__ q, float* __restrict__ k,
                                             float* __restrict__ v) {
    int t = blockIdx.x, c = threadIdx.x;
    __shared__ float zs[128];
    zs[c] = z[t * 128 + c];
    __syncthreads();
    float aq = bq[c], ak = bk[c], av = bv[c];
    for (int kk = 0; kk < 128; ++kk) {
        float zv = zs[kk];
        aq += zv * Wq[(kk << 7) + c];
        ak += zv * Wk[(kk << 7) + c];
        av += zv * Wv[(kk << 7) + c];
    }
    q[t * 128 + c] = aq;
    k[t * 128 + c] = ak;
    v[t * 128 + c] = av;
}

// ---------------- head stage 2 ----------------
__global__ __launch_bounds__(256) void k_attnmid(
    const float* __restrict__ q, const float* __restrict__ k, const float* __restrict__ v,
    const float* __restrict__ Wo, const float* __restrict__ bo,
    const float* __restrict__ g2, const float* __restrict__ beta2,
    const float* __restrict__ Wm1, const float* __restrict__ bm1,
    const float* __restrict__ Wm2, const float* __restrict__ bm2,
    float* __restrict__ xr) {
    int t = blockIdx.x, tid = threadIdx.x;
    __shared__ float Ks[32 * 128], Vs[32 * 128];
    __shared__ float qs[128], sc[8 * 32], xa[128], hid[512], ys[128];
    __shared__ float redA[128], redB[128];

    for (int i = tid; i < 32 * 128; i += 256) { Ks[i] = k[i]; Vs[i] = v[i]; }
    if (tid < 128) qs[tid] = q[t * 128 + tid];
    __syncthreads();

    {
        int h = tid >> 5, s = tid & 31;
        float d = 0.0f;
#pragma unroll
        for (int kk = 0; kk < 16; ++kk)
            d += qs[(h << 4) + kk] * Ks[(s << 7) + (h << 4) + kk];
        sc[tid] = d * 0.25f;
    }
    __syncthreads();
    if (tid < 8) {
        float m = -1e30f;
        for (int s = 0; s < 32; ++s) m = fmaxf(m, sc[(tid << 5) + s]);
        float l = 0.0f;
        for (int s = 0; s < 32; ++s) { float e = __expf(sc[(tid << 5) + s] - m); sc[(tid << 5) + s] = e; l += e; }
        float inv = 1.0f / l;
        for (int s = 0; s < 32; ++s) sc[(tid << 5) + s] *= inv;
    }
    __syncthreads();
    if (tid < 128) {
        int h = tid >> 4;
        float o = 0.0f;
        for (int s = 0; s < 32; ++s) o += sc[(h << 5) + s] * Vs[(s << 7) + tid];
        qs[tid] = o;
    }
    __syncthreads();
    if (tid < 128) {
        float a = bo[tid];
        for (int kk = 0; kk < 128; ++kk) a += qs[kk] * Wo[(kk << 7) + tid];
        xa[tid] = a;
    }
    __syncthreads();
    for (int j = tid; j < 512; j += 256) {
        float a = bm1[j];
        for (int kk = 0; kk < 128; ++kk) a += xa[kk] * Wm1[(kk << 9) + j];
        hid[j] = fmaxf(a, 0.0f);
    }
    __syncthreads();
    if (tid < 128) {
        float a = bm2[tid];
        for (int j = 0; j < 512; ++j) a += hid[j] * Wm2[(j << 7) + tid];
        ys[tid] = xa[tid] + a;
    }
    __syncthreads();
    if (tid < 128) { redA[tid] = ys[tid]; redB[tid] = ys[tid] * ys[tid]; }
    __syncthreads();
    for (int off = 64; off > 0; off >>= 1) {
        if (tid < off) { redA[tid] += redA[tid + off]; redB[tid] += redB[tid + off]; }
        __syncthreads();
    }
    float mu = redA[0] * (1.0f / 128.0f);
    float var = redB[0] * (1.0f / 128.0f) - mu * mu;
    float rs = rsqrtf(var + 1e-5f);
    if (tid < 128) {
        float yv = (ys[tid] - mu) * rs * g2[tid] + beta2[tid];
        xr[t * 128 + tid] = fmaxf(yv, 0.0f);
    }
}

// ---------------- head stage 3 ----------------
__global__ __launch_bounds__(128) void k_final(const float* __restrict__ xr,
                                               const float* __restrict__ Wl,
                                               const float* __restrict__ bl,
                                               float* __restrict__ out) {
    int tid = threadIdx.x;
    __shared__ float pooled[128];
    float s = 0.0f;
    for (int t = 0; t < 32; ++t) s += xr[t * 128 + tid];
    pooled[tid] = s;
    __syncthreads();
    if (tid < C_) {
        float a = bl[tid];
        for (int kk = 0; kk < 128; ++kk) a += pooled[kk] * Wl[kk * C_ + tid];
        out[tid] = a;
    }
}

extern "C" void kernel_launch(void* const* d_in, const int* in_sizes, int n_in,
                              void* d_out, int out_size, void* d_ws, size_t ws_size,
                              hipStream_t stream) {
    const float* x  = (const float*)d_in[0];
    const int*   ei = (const int*)d_in[1];
    const float* W0 = (const float*)d_in[2];  const float* b0 = (const float*)d_in[3];
    const float* W1 = (const float*)d_in[4];  const float* b1 = (const float*)d_in[5];
    const float* W2 = (const float*)d_in[6];  const float* b2 = (const float*)d_in[7];
    const float* Wq = (const float*)d_in[8];  const float* bq = (const float*)d_in[9];
    const float* Wk = (const float*)d_in[10]; const float* bk = (const float*)d_in[11];
    const float* Wv = (const float*)d_in[12]; const float* bv = (const float*)d_in[13];
    const float* Wo = (const float*)d_in[14]; const float* bo = (const float*)d_in[15];
    const float* g2 = (const float*)d_in[16]; const float* beta2 = (const float*)d_in[17];
    const float* Wm1 = (const float*)d_in[18]; const float* bm1 = (const float*)d_in[19];
    const float* Wm2 = (const float*)d_in[20]; const float* bm2 = (const float*)d_in[21];
    const float* Wl = (const float*)d_in[22]; const float* bl = (const float*)d_in[23];
    float* outp = (float*)d_out;

    const size_t BIG = (size_t)T_ * N_ * H_;
    char* ws = (char*)d_ws;
    float*    dinv = (float*)(ws);
    int*      ptr  = (int*)(ws + 640000);
    uint16_t* col  = (uint16_t*)(ws + 1280000);
    f16*      Wt   = (f16*)(ws + 6400000);
    f16*      P16  = (f16*)(ws + 6498304);
    f16*      Q16  = P16 + BIG;
    float*    z    = (float*)(Q16 + BIG);   // [0..4095] accum; [4096..4159] zerorow (row ZROW_ rel P16)
    float*    zq   = z + 4096 + 64;
    float*    zk   = zq + 4096;
    float*    zv   = zk + 4096;
    float*    xr   = zv + 4096;
    int*      part = (int*)P16;   // CSR partials alias P16 (used only before first gemm)

    k_wprep<<<3, 256, 0, stream>>>(W0, W1, W2, Wt);
    k_count<<<NB_ * 32, 256, 0, stream>>>(ei, part);
    k_scan<<<T_, 256, 0, stream>>>(part, ptr, dinv, z);
    k_scatter<<<NB_ * 32, 256, 0, stream>>>(ei, part, col);

    const int AGGR_BLOCKS = NB64_ * 32;   // 64 nodes/block, 4 quads/wave
    k_gemm<true><<<GEMMB, 256, 0, stream>>>(x, Wt, dinv, P16);
    k_aggr<<<AGGR_BLOCKS, 256, 0, stream>>>(ptr, col, P16, dinv, b0, Q16);
    k_gemm<false><<<GEMMB, 256, 0, stream>>>(Q16, Wt + 16384, dinv, P16);
    k_aggr<<<AGGR_BLOCKS, 256, 0, stream>>>(ptr, col, P16, dinv, b1, Q16);
    k_gemm<false><<<GEMMB, 256, 0, stream>>>(Q16, Wt + 32768, dinv, P16);
    k_aggr<<<AGGR_BLOCKS, 256, 0, stream>>>(ptr, col, P16, dinv, b2, Q16);

    k_reduce<<<dim3(T_, 10), 256, 0, stream>>>(Q16, z);

    k_qkv<<<T_, 128, 0, stream>>>(z, Wq, bq, Wk, bk, Wv, bv, zq, zk, zv);
    k_attnmid<<<T_, 256, 0, stream>>>(zq, zk, zv, Wo, bo, g2, beta2,
                                      Wm1, bm1, Wm2, bm2, xr);
    k_final<<<1, 128, 0, stream>>>(xr, Wl, bl, outp);
}

// Round 13
// 495.670 us; speedup vs baseline: 2.7475x; 1.0040x over previous
//
#include <hip/hip_runtime.h>
#include <cstdint>

#define T_ 32
#define N_ 5000
#define E_ 80000
#define H_ 128
#define HD_ 512
#define C_ 10

typedef _Float16 f16;
typedef f16 f16x8 __attribute__((ext_vector_type(8)));
typedef f16 f16x4 __attribute__((ext_vector_type(4)));
typedef f16 f16x2 __attribute__((ext_vector_type(2)));
typedef float f32x4 __attribute__((ext_vector_type(4)));

#define LDA 136   // padded LDS leading dim in f16
#define NB_ 8     // CSR-build blocks per graph
#define EPS_ (E_ / NB_)  // 10000 edges per block
#define NBLK_ 313 // ceil(N_/16) 16-row blocks per graph (gemm tasks + aggr)
#define GEMMB 768 // gemm grid: 96 blocks/XCD * 8
#define ZROW_ 320064  // zero-row index rel. to P16: (2*BIG + 8192 f16)/128

__device__ inline float fast_tanh(float x) {
    return 1.0f - 2.0f / (__expf(2.0f * x) + 1.0f);
}

__device__ inline f16x8 cvt8(float4 a, float4 b) {
    return (f16x8){(f16)a.x, (f16)a.y, (f16)a.z, (f16)a.w,
                   (f16)b.x, (f16)b.y, (f16)b.z, (f16)b.w};
}

// ---------------- CSR build, LDS-atomic (no global atomics) ----------------
__global__ __launch_bounds__(256) void k_count(const int* __restrict__ ei, int* __restrict__ part) {
    __shared__ int cnt[N_];
    int blk = blockIdx.x;
    int t = blk & 31, seg = blk >> 5;
    int tid = threadIdx.x;
    for (int i = tid; i < N_; i += 256) cnt[i] = 0;
    __syncthreads();
    const int* dst = ei + (size_t)t * 2 * E_ + E_ + seg * EPS_;
    for (int e = tid * 4; e < EPS_; e += 1024) {
        int4 d = *(const int4*)&dst[e];
        atomicAdd(&cnt[d.x], 1);
        atomicAdd(&cnt[d.y], 1);
        atomicAdd(&cnt[d.z], 1);
        atomicAdd(&cnt[d.w], 1);
    }
    __syncthreads();
    int* p = part + (t * NB_ + seg) * N_;
    for (int i = tid * 4; i < N_; i += 1024) *(int4*)&p[i] = *(const int4*)&cnt[i];
}

// ---------------- scan v2: coalesced degree/fixup phases, LDS-staged scan ----------------
// Also zeroes z (node-sum accumulator) and the dedicated zerorow (gather
// redirect target; z+4096 floats; never written afterwards).
__global__ __launch_bounds__(256) void k_scan(int* __restrict__ part, int* __restrict__ ptr,
                                              float* __restrict__ dinv, float* __restrict__ z) {
    __shared__ int cnt[N_];      // degree, then start offset
    __shared__ int red[256];
    int t = blockIdx.x, tid = threadIdx.x;
    int base = t * N_;
    if (tid < 128) z[t * 128 + tid] = 0.0f;            // accumulator zero-init
    if (tid >= 128 && tid < 192) z[4096 + (tid - 128)] = 0.0f;  // zerorow (benign multi-block)
    int* pp = part + t * NB_ * N_;

    // Phase A: coalesced degree computation
    for (int i = tid; i < N_; i += 256) {
        int c = 0;
#pragma unroll
        for (int s = 0; s < NB_; ++s) c += pp[s * N_ + i];
        cnt[i] = c;
        dinv[base + i] = rsqrtf((float)(c + 1));  // +1 self-loop
    }
    __syncthreads();

    // Phase B: block scan over blocked 20-element runs (LDS source)
    int vals[20];
    int sum = 0;
#pragma unroll
    for (int j = 0; j < 20; ++j) {
        int i = tid * 20 + j;
        int c = (i < N_) ? cnt[i] : 0;
        vals[j] = sum;
        sum += c;
    }
    red[tid] = sum;
    __syncthreads();
    for (int off = 1; off < 256; off <<= 1) {
        int v = (tid >= off) ? red[tid - off] : 0;
        __syncthreads();
        red[tid] += v;
        __syncthreads();
    }
    int prev = (tid > 0) ? red[tid - 1] : 0;
#pragma unroll
    for (int j = 0; j < 20; ++j) {
        int i = tid * 20 + j;
        if (i < N_) cnt[i] = prev + vals[j];   // overwrite degree with start offset
    }
    __syncthreads();

    // Phase C: coalesced ptr write + per-segment running-offset fixup
    for (int i = tid; i < N_; i += 256) {
        int run = cnt[i];
        ptr[base + i] = run;
#pragma unroll
        for (int s = 0; s < NB_; ++s) {
            int c = pp[s * N_ + i];
            pp[s * N_ + i] = run;
            run += c;
        }
    }
}

__global__ __launch_bounds__(256) void k_scatter(const int* __restrict__ ei,
                                                 const int* __restrict__ part,
                                                 uint16_t* __restrict__ col) {
    __shared__ int cur[N_];
    int blk = blockIdx.x;
    int t = blk & 31, seg = blk >> 5;
    int tid = threadIdx.x;
    const int* off = part + (t * NB_ + seg) * N_;
    for (int i = tid * 4; i < N_; i += 1024) *(int4*)&cur[i] = *(const int4*)&off[i];
    __syncthreads();
    const int* src = ei + (size_t)t * 2 * E_ + seg * EPS_;
    const int* dst = src + E_;
    uint16_t* cl = col + (size_t)t * E_;
    for (int e = tid * 4; e < EPS_; e += 1024) {
        int4 s4 = *(const int4*)&src[e];
        int4 d4 = *(const int4*)&dst[e];
        cl[atomicAdd(&cur[d4.x], 1)] = (uint16_t)s4.x;
        cl[atomicAdd(&cur[d4.y], 1)] = (uint16_t)s4.y;
        cl[atomicAdd(&cur[d4.z], 1)] = (uint16_t)s4.z;
        cl[atomicAdd(&cur[d4.w], 1)] = (uint16_t)s4.w;
    }
}

// ---------------- weight prep: Wt[l][c][k] = (f16)W_l[k][c] ----------------
__global__ __launch_bounds__(256) void k_wprep(const float* __restrict__ W0,
                                               const float* __restrict__ W1,
                                               const float* __restrict__ W2,
                                               f16* __restrict__ Wt) {
    const float* W = (blockIdx.x == 0) ? W0 : (blockIdx.x == 1) ? W1 : W2;
    f16* dst = Wt + blockIdx.x * 16384;
    for (int idx = threadIdx.x; idx < 16384; idx += 256) {
        int c = idx >> 7, k = idx & 127;
        dst[idx] = (f16)W[k * 128 + c];
    }
}

// ---------------- MFMA GEMM v5: barrier-free streaming (measured keeper) ----------------
// K=128 fits one wave's MFMA fragments: no inter-wave A sharing. Stage Ws once ->
// ONE barrier -> waves grid-stride independent 16-row tasks; A direct global->reg;
// transpose via per-wave private LDS slab (lgkmcnt only); 1KB coalesced stores.
template <bool F32IN>
__global__ __launch_bounds__(256, 3) void k_gemm(const void* __restrict__ in_,
                                                 const f16* __restrict__ Wt,  // [c][k]
                                                 const float* __restrict__ dinv,
                                                 f16* __restrict__ g) {
    __shared__ f16 Ws[128 * LDA];
    __shared__ f16 slab[4][16 * LDA];
    int tid = threadIdx.x;
    {
        int c = tid >> 1, hf = tid & 1;
        const f16* src = Wt + c * 128 + hf * 64;
        f16* dst = Ws + c * LDA + hf * 64;
#pragma unroll
        for (int j = 0; j < 8; ++j) *(f16x8*)&dst[j * 8] = *(const f16x8*)&src[j * 8];
    }
    __syncthreads();   // the ONLY barrier; waves run free below

    int xc = blockIdx.x & 7;
    int jb = blockIdx.x >> 3;            // 0..95 per XCD
    int w = tid >> 6, lane = tid & 63;
    int m = lane & 15, q = lane >> 4;
    int co = q * 8;
    f16* sl = slab[w];
    int srow = lane >> 4;                // store row-within-quad
    int scol = (lane & 15) * 8;          // store col

    for (int task = jb * 4 + w; task < 4 * NBLK_; task += 384) {
        int gsel = task / NBLK_;
        int tile = task - gsel * NBLK_;
        int t = xc + (gsel << 3);
        int base = t * N_;
        int r0 = tile * 16;
        int rowA = r0 + m; if (rowA >= N_) rowA = N_ - 1;   // clamp (not stored)

        // A fragments: direct global -> registers
        f16x8 a0, a1, a2, a3;
        if (F32IN) {
            const float* src = (const float*)in_ + (((size_t)(base + rowA)) << 7) + co;
            float4 u0 = *(const float4*)&src[0];
            float4 u1 = *(const float4*)&src[4];
            float4 u2 = *(const float4*)&src[32];
            float4 u3 = *(const float4*)&src[36];
            float4 u4 = *(const float4*)&src[64];
            float4 u5 = *(const float4*)&src[68];
            float4 u6 = *(const float4*)&src[96];
            float4 u7 = *(const float4*)&src[100];
            a0 = cvt8(u0, u1); a1 = cvt8(u2, u3); a2 = cvt8(u4, u5); a3 = cvt8(u6, u7);
        } else {
            const f16* src = (const f16*)in_ + (((size_t)(base + rowA)) << 7) + co;
            a0 = *(const f16x8*)&src[0];
            a1 = *(const f16x8*)&src[32];
            a2 = *(const f16x8*)&src[64];
            a3 = *(const f16x8*)&src[96];
        }

        f32x4 acc[8];
#pragma unroll
        for (int n = 0; n < 8; ++n) acc[n] = (f32x4){0.f, 0.f, 0.f, 0.f};
#pragma unroll
        for (int n = 0; n < 8; ++n) {
            f16x8 bF = *(const f16x8*)&Ws[(n * 16 + m) * LDA + co];
            acc[n] = __builtin_amdgcn_mfma_f32_16x16x32_f16(a0, bF, acc[n], 0, 0, 0);
        }
#pragma unroll
        for (int n = 0; n < 8; ++n) {
            f16x8 bF = *(const f16x8*)&Ws[(n * 16 + m) * LDA + 32 + co];
            acc[n] = __builtin_amdgcn_mfma_f32_16x16x32_f16(a1, bF, acc[n], 0, 0, 0);
        }
#pragma unroll
        for (int n = 0; n < 8; ++n) {
            f16x8 bF = *(const f16x8*)&Ws[(n * 16 + m) * LDA + 64 + co];
            acc[n] = __builtin_amdgcn_mfma_f32_16x16x32_f16(a2, bF, acc[n], 0, 0, 0);
        }
#pragma unroll
        for (int n = 0; n < 8; ++n) {
            f16x8 bF = *(const f16x8*)&Ws[(n * 16 + m) * LDA + 96 + co];
            acc[n] = __builtin_amdgcn_mfma_f32_16x16x32_f16(a3, bF, acc[n], 0, 0, 0);
        }

        // epilogue: dinv scale -> per-wave slab (transpose) -> coalesced store
#pragma unroll
        for (int i = 0; i < 4; ++i) {
            int rr = q * 4 + i;
            int gr = r0 + rr; if (gr >= N_) gr = N_ - 1;
            float d = dinv[base + gr];
#pragma unroll
            for (int n = 0; n < 8; ++n)
                sl[rr * LDA + n * 16 + m] = (f16)(acc[n][i] * d);
        }
        asm volatile("s_waitcnt lgkmcnt(0)" ::: "memory");  // wave-internal write->read fence
#pragma unroll
        for (int j4 = 0; j4 < 4; ++j4) {
            int row = j4 * 4 + srow;
            f16x8 v = *(const f16x8*)&sl[row * LDA + scol];
            if (r0 + row < N_)
                *(f16x8*)&g[(((size_t)(base + r0 + row)) << 7) + scol] = v;  // 1KB/wave contiguous
        }
    }
}

// ---------------- CSR gather v4 (measured best; layers 1 & 2) ----------------
// 16 nodes/block, 4 nodes/wave, barrier-free. The gather loop is at the
// random-256B-row L2 floor (~12 TB/s effective): three pipelining attempts and
// two blocking variants all landed 55.5-62.8us. Do not touch.
// Out-of-range lanes redirect via ONE cndmask to the dedicated zerorow
// (z+4096 floats; row ZROW_-5000t rel. to gg=P16; zeroed by k_scan).
__global__ __launch_bounds__(256) void k_aggr(const int* __restrict__ ptr,
                                              const uint16_t* __restrict__ col,
                                              const f16* __restrict__ g,
                                              const float* __restrict__ dinv,
                                              const float* __restrict__ b,
                                              f16* __restrict__ out) {
    int x = blockIdx.x & 7;
    int j = blockIdx.x >> 3;
    int gsel = j / NBLK_;
    int nb = j - gsel * NBLK_;
    int t = x + (gsel << 3);

    int w = threadIdx.x >> 6;
    int lane = threadIdx.x & 63;
    int q = lane >> 4, m = lane & 15;
    int n0 = nb * 16 + w * 4;    // wave's first node (4-aligned)
    if (n0 >= N_) return;        // tail waves (no barriers in this kernel)
    int base = t * N_;
    const f16* gg = g + (size_t)base * H_;
    const uint16_t* cl = col + (size_t)t * E_;
    int n = n0 + q;              // this 16-lane group's node
    unsigned moB = (unsigned)(m * 8);   // lane's 8-col slice (element offset)

    int4 p4 = *(const int4*)&ptr[base + n0];
    int pend = (n0 + 4 < N_) ? ptr[base + n0 + 4] : E_;
    int begin = (q == 0) ? p4.x : (q == 1) ? p4.y : (q == 2) ? p4.z : p4.w;
    int end   = (q == 0) ? p4.y : (q == 1) ? p4.z : (q == 2) ? p4.w : pend;

    float dn = dinv[base + n];
    float4 b4a = *(const float4*)&b[m * 8];
    float4 b4b = *(const float4*)&b[m * 8 + 4];

    int zidx = ZROW_ - 5000 * t;

    f16x8 a0 = *(const f16x8*)&gg[((unsigned)n << 7) + moB];  // self-loop row
    f16x8 a1 = {}, a2 = {}, a3 = {}, a4 = {}, a5 = {}, a6 = {}, a7 = {};

    int e0 = begin & ~7;
    int elast = (end - 1) & ~7;
    unsigned span = (unsigned)(end - begin);
    uint4 cc = *(const uint4*)&cl[e0];
    for (int e = e0; e < end; e += 8) {
        int en = e + 8;
        int epf = en < elast ? en : elast;
        uint4 cn = *(const uint4*)&cl[epf];
        unsigned eb = (unsigned)(e - begin);
        int i0 = (int)(cc.x & 0xFFFFu), i1 = (int)(cc.x >> 16);
        int i2 = (int)(cc.y & 0xFFFFu), i3 = (int)(cc.y >> 16);
        int i4 = (int)(cc.z & 0xFFFFu), i5 = (int)(cc.z >> 16);
        int i6 = (int)(cc.w & 0xFFFFu), i7 = (int)(cc.w >> 16);
        int s0 = (eb + 0 < span) ? i0 : zidx;
        int s1 = (eb + 1 < span) ? i1 : zidx;
        int s2 = (eb + 2 < span) ? i2 : zidx;
        int s3 = (eb + 3 < span) ? i3 : zidx;
        int s4 = (eb + 4 < span) ? i4 : zidx;
        int s5 = (eb + 5 < span) ? i5 : zidx;
        int s6 = (eb + 6 < span) ? i6 : zidx;
        int s7 = (eb + 7 < span) ? i7 : zidx;
        f16x8 v0 = *(const f16x8*)&gg[((unsigned)s0 << 7) + moB];
        f16x8 v1 = *(const f16x8*)&gg[((unsigned)s1 << 7) + moB];
        f16x8 v2 = *(const f16x8*)&gg[((unsigned)s2 << 7) + moB];
        f16x8 v3 = *(const f16x8*)&gg[((unsigned)s3 << 7) + moB];
        f16x8 v4 = *(const f16x8*)&gg[((unsigned)s4 << 7) + moB];
        f16x8 v5 = *(const f16x8*)&gg[((unsigned)s5 << 7) + moB];
        f16x8 v6 = *(const f16x8*)&gg[((unsigned)s6 << 7) + moB];
        f16x8 v7 = *(const f16x8*)&gg[((unsigned)s7 << 7) + moB];
        a0 += v0; a1 += v1; a2 += v2; a3 += v3;
        a4 += v4; a5 += v5; a6 += v6; a7 += v7;
        cc = cn;
    }
    a0 += a1; a2 += a3; a4 += a5; a6 += a7;
    a0 += a2; a4 += a6;
    a0 += a4;

    f16x8 o;
#pragma unroll
    for (int jj = 0; jj < 8; ++jj) {
        float bj = (jj < 4) ? ((const float*)&b4a)[jj] : ((const float*)&b4b)[jj - 4];
        o[jj] = (f16)fast_tanh(dn * (float)a0[jj] + bj);
    }
    *(f16x8*)&out[((size_t)base + n) * H_ + moB] = o;  // contiguous 1 KB wave store
}

// ---------------- CSR gather + per-BLOCK partial sum (final layer) ----------------
// Same v4 gather; instead of the 40MB h3 store (consumed only by the node-sum),
// each wave shfl-reduces its 4 nodes' tanh outputs (named scalars), writes its
// 128-col partial to LDS, ONE end-of-kernel barrier, then tid<128 sums the 4
// wave partials and plain-stores a per-block partial (NO atomics -- v11's
// per-wave atomics serialized 1250-deep/address, 936us). k_zred sums the 313
// partials per (t,c). Saves aggr3's 40MB write + k_reduce's 40MB read.
// Tail waves (n0>=N_) contribute zeros but DO reach the barrier.
__global__ __launch_bounds__(256) void k_aggr_red2(const int* __restrict__ ptr,
                                                   const uint16_t* __restrict__ col,
                                                   const f16* __restrict__ g,
                                                   const float* __restrict__ dinv,
                                                   const float* __restrict__ b,
                                                   float* __restrict__ partial) {
    __shared__ float sh[4][128];
    int x = blockIdx.x & 7;
    int j = blockIdx.x >> 3;
    int gsel = j / NBLK_;
    int nb = j - gsel * NBLK_;
    int t = x + (gsel << 3);

    int tid = threadIdx.x;
    int w = tid >> 6;
    int lane = tid & 63;
    int q = lane >> 4, m = lane & 15;
    int n0 = nb * 16 + w * 4;
    bool wvalid = n0 < N_;       // tail waves still reach the barrier
    int base = t * N_;
    const f16* gg = g + (size_t)base * H_;
    const uint16_t* cl = col + (size_t)t * E_;
    int n = wvalid ? (n0 + q) : (N_ - 1);   // safe address; contribution zeroed below
    unsigned moB = (unsigned)(m * 8);

    int begin = 0, end = 0;
    float dn = 0.0f;
    if (wvalid) {
        int4 p4 = *(const int4*)&ptr[base + n0];
        int pend = (n0 + 4 < N_) ? ptr[base + n0 + 4] : E_;
        begin = (q == 0) ? p4.x : (q == 1) ? p4.y : (q == 2) ? p4.z : p4.w;
        end   = (q == 0) ? p4.y : (q == 1) ? p4.z : (q == 2) ? p4.w : pend;
        dn = dinv[base + n];
    }
    float4 b4a = *(const float4*)&b[m * 8];
    float4 b4b = *(const float4*)&b[m * 8 + 4];
    int zidx = ZROW_ - 5000 * t;

    f16x8 a0 = {};
    if (wvalid) a0 = *(const f16x8*)&gg[((unsigned)n << 7) + moB];  // self-loop row
    f16x8 a1 = {}, a2 = {}, a3 = {}, a4 = {}, a5 = {}, a6 = {}, a7 = {};

    if (wvalid && begin < end) {
        int e0 = begin & ~7;
        int elast = (end - 1) & ~7;
        unsigned span = (unsigned)(end - begin);
        uint4 cc = *(const uint4*)&cl[e0];
        for (int e = e0; e < end; e += 8) {
            int en = e + 8;
            int epf = en < elast ? en : elast;
            uint4 cn = *(const uint4*)&cl[epf];
            unsigned eb = (unsigned)(e - begin);
            int i0 = (int)(cc.x & 0xFFFFu), i1 = (int)(cc.x >> 16);
            int i2 = (int)(cc.y & 0xFFFFu), i3 = (int)(cc.y >> 16);
            int i4 = (int)(cc.z & 0xFFFFu), i5 = (int)(cc.z >> 16);
            int i6 = (int)(cc.w & 0xFFFFu), i7 = (int)(cc.w >> 16);
            int s0 = (eb + 0 < span) ? i0 : zidx;
            int s1 = (eb + 1 < span) ? i1 : zidx;
            int s2 = (eb + 2 < span) ? i2 : zidx;
            int s3 = (eb + 3 < span) ? i3 : zidx;
            int s4 = (eb + 4 < span) ? i4 : zidx;
            int s5 = (eb + 5 < span) ? i5 : zidx;
            int s6 = (eb + 6 < span) ? i6 : zidx;
            int s7 = (eb + 7 < span) ? i7 : zidx;
            f16x8 v0 = *(const f16x8*)&gg[((unsigned)s0 << 7) + moB];
            f16x8 v1 = *(const f16x8*)&gg[((unsigned)s1 << 7) + moB];
            f16x8 v2 = *(const f16x8*)&gg[((unsigned)s2 << 7) + moB];
            f16x8 v3 = *(const f16x8*)&gg[((unsigned)s3 << 7) + moB];
            f16x8 v4 = *(const f16x8*)&gg[((unsigned)s4 << 7) + moB];
            f16x8 v5 = *(const f16x8*)&gg[((unsigned)s5 << 7) + moB];
            f16x8 v6 = *(const f16x8*)&gg[((unsigned)s6 << 7) + moB];
            f16x8 v7 = *(const f16x8*)&gg[((unsigned)s7 << 7) + moB];
            a0 += v0; a1 += v1; a2 += v2; a3 += v3;
            a4 += v4; a5 += v5; a6 += v6; a7 += v7;
            cc = cn;
        }
    }
    a0 += a1; a2 += a3; a4 += a5; a6 += a7;
    a0 += a2; a4 += a6;
    a0 += a4;

    // tanh (f16-rounded to match stored-value semantics), zeroed for tail waves
    float s0_ = 0.f, s1_ = 0.f, s2_ = 0.f, s3_ = 0.f, s4_ = 0.f, s5_ = 0.f, s6_ = 0.f, s7_ = 0.f;
    if (wvalid) {
        s0_ = (float)(f16)fast_tanh(dn * (float)a0[0] + ((const float*)&b4a)[0]);
        s1_ = (float)(f16)fast_tanh(dn * (float)a0[1] + ((const float*)&b4a)[1]);
        s2_ = (float)(f16)fast_tanh(dn * (float)a0[2] + ((const float*)&b4a)[2]);
        s3_ = (float)(f16)fast_tanh(dn * (float)a0[3] + ((const float*)&b4a)[3]);
        s4_ = (float)(f16)fast_tanh(dn * (float)a0[4] + ((const float*)&b4b)[0]);
        s5_ = (float)(f16)fast_tanh(dn * (float)a0[5] + ((const float*)&b4b)[1]);
        s6_ = (float)(f16)fast_tanh(dn * (float)a0[6] + ((const float*)&b4b)[2]);
        s7_ = (float)(f16)fast_tanh(dn * (float)a0[7] + ((const float*)&b4b)[3]);
    }
    // sum across the wave's 4 nodes (lanes differ only in q for fixed m)
    s0_ += __shfl_xor(s0_, 16, 64); s0_ += __shfl_xor(s0_, 32, 64);
    s1_ += __shfl_xor(s1_, 16, 64); s1_ += __shfl_xor(s1_, 32, 64);
    s2_ += __shfl_xor(s2_, 16, 64); s2_ += __shfl_xor(s2_, 32, 64);
    s3_ += __shfl_xor(s3_, 16, 64); s3_ += __shfl_xor(s3_, 32, 64);
    s4_ += __shfl_xor(s4_, 16, 64); s4_ += __shfl_xor(s4_, 32, 64);
    s5_ += __shfl_xor(s5_, 16, 64); s5_ += __shfl_xor(s5_, 32, 64);
    s6_ += __shfl_xor(s6_, 16, 64); s6_ += __shfl_xor(s6_, 32, 64);
    s7_ += __shfl_xor(s7_, 16, 64); s7_ += __shfl_xor(s7_, 32, 64);
    if (q == 0) {
        float* sp = &sh[w][m * 8];
        sp[0] = s0_; sp[1] = s1_; sp[2] = s2_; sp[3] = s3_;
        sp[4] = s4_; sp[5] = s5_; sp[6] = s6_; sp[7] = s7_;
    }
    __syncthreads();   // only barrier; post-barrier work is ~10 instructions
    if (tid < 128) {
        float s = sh[0][tid] + sh[1][tid] + sh[2][tid] + sh[3][tid];
        partial[((size_t)(t * NBLK_ + nb)) * 128 + tid] = s;   // coalesced, no atomics
    }
}

// ---------------- z reduction: z[t][c] = sum over 313 block partials ----------------
__global__ __launch_bounds__(128) void k_zred(const float* __restrict__ partial,
                                              float* __restrict__ z) {
    int t = blockIdx.x, c = threadIdx.x;
    const float* p = partial + (size_t)t * NBLK_ * 128 + c;
    float s = 0.0f;
    for (int nb = 0; nb < NBLK_; ++nb) s += p[nb * 128];
    z[t * 128 + c] = s;
}

// ---------------- head stage 1: q,k,v ----------------
__global__ __launch_bounds__(128) void k_qkv(const float* __restrict__ z,
                                             const float* __restrict__ Wq, const float* __restrict__ bq,
                                             const float* __restrict__ Wk, const float* __restrict__ bk,
                                             const float* __restrict__ Wv, const float* __restrict__ bv,
                                             float* __restrict__ q, float* __restrict__ k,
                                             float* __restrict__ v) {
    int t = blockIdx.x, c = threadIdx.x;
    __shared__ float zs[128];
    zs[c] = z[t * 128 + c];
    __syncthreads();
    float aq = bq[c], ak = bk[c], av = bv[c];
    for (int kk = 0; kk < 128; ++kk) {
        float zv = zs[kk];
        aq += zv * Wq[(kk << 7) + c];
        ak += zv * Wk[(kk << 7) + c];
        av += zv * Wv[(kk << 7) + c];
    }
    q[t * 128 + c] = aq;
    k[t * 128 + c] = ak;
    v[t * 128 + c] = av;
}

// ---------------- head stage 2 ----------------
__global__ __launch_bounds__(256) void k_attnmid(
    const float* __restrict__ q, const float* __restrict__ k, const float* __restrict__ v,
    const float* __restrict__ Wo, const float* __restrict__ bo,
    const float* __restrict__ g2, const float* __restrict__ beta2,
    const float* __restrict__ Wm1, const float* __restrict__ bm1,
    const float* __restrict__ Wm2, const float* __restrict__ bm2,
    float* __restrict__ xr) {
    int t = blockIdx.x, tid = threadIdx.x;
    __shared__ float Ks[32 * 128], Vs[32 * 128];
    __shared__ float qs[128], sc[8 * 32], xa[128], hid[512], ys[128];
    __shared__ float redA[128], redB[128];

    for (int i = tid; i < 32 * 128; i += 256) { Ks[i] = k[i]; Vs[i] = v[i]; }
    if (tid < 128) qs[tid] = q[t * 128 + tid];
    __syncthreads();

    {
        int h = tid >> 5, s = tid & 31;
        float d = 0.0f;
#pragma unroll
        for (int kk = 0; kk < 16; ++kk)
            d += qs[(h << 4) + kk] * Ks[(s << 7) + (h << 4) + kk];
        sc[tid] = d * 0.25f;
    }
    __syncthreads();
    if (tid < 8) {
        float m = -1e30f;
        for (int s = 0; s < 32; ++s) m = fmaxf(m, sc[(tid << 5) + s]);
        float l = 0.0f;
        for (int s = 0; s < 32; ++s) { float e = __expf(sc[(tid << 5) + s] - m); sc[(tid << 5) + s] = e; l += e; }
        float inv = 1.0f / l;
        for (int s = 0; s < 32; ++s) sc[(tid << 5) + s] *= inv;
    }
    __syncthreads();
    if (tid < 128) {
        int h = tid >> 4;
        float o = 0.0f;
        for (int s = 0; s < 32; ++s) o += sc[(h << 5) + s] * Vs[(s << 7) + tid];
        qs[tid] = o;
    }
    __syncthreads();
    if (tid < 128) {
        float a = bo[tid];
        for (int kk = 0; kk < 128; ++kk) a += qs[kk] * Wo[(kk << 7) + tid];
        xa[tid] = a;
    }
    __syncthreads();
    for (int j = tid; j < 512; j += 256) {
        float a = bm1[j];
        for (int kk = 0; kk < 128; ++kk) a += xa[kk] * Wm1[(kk << 9) + j];
        hid[j] = fmaxf(a, 0.0f);
    }
    __syncthreads();
    if (tid < 128) {
        float a = bm2[tid];
        for (int j = 0; j < 512; ++j) a += hid[j] * Wm2[(j << 7) + tid];
        ys[tid] = xa[tid] + a;
    }
    __syncthreads();
    if (tid < 128) { redA[tid] = ys[tid]; redB[tid] = ys[tid] * ys[tid]; }
    __syncthreads();
    for (int off = 64; off > 0; off >>= 1) {
        if (tid < off) { redA[tid] += redA[tid + off]; redB[tid] += redB[tid + off]; }
        __syncthreads();
    }
    float mu = redA[0] * (1.0f / 128.0f);
    float var = redB[0] * (1.0f / 128.0f) - mu * mu;
    float rs = rsqrtf(var + 1e-5f);
    if (tid < 128) {
        float yv = (ys[tid] - mu) * rs * g2[tid] + beta2[tid];
        xr[t * 128 + tid] = fmaxf(yv, 0.0f);
    }
}

// ---------------- head stage 3 ----------------
__global__ __launch_bounds__(128) void k_final(const float* __restrict__ xr,
                                               const float* __restrict__ Wl,
                                               const float* __restrict__ bl,
                                               float* __restrict__ out) {
    int tid = threadIdx.x;
    __shared__ float pooled[128];
    float s = 0.0f;
    for (int t = 0; t < 32; ++t) s += xr[t * 128 + tid];
    pooled[tid] = s;
    __syncthreads();
    if (tid < C_) {
        float a = bl[tid];
        for (int kk = 0; kk < 128; ++kk) a += pooled[kk] * Wl[kk * C_ + tid];
        out[tid] = a;
    }
}

extern "C" void kernel_launch(void* const* d_in, const int* in_sizes, int n_in,
                              void* d_out, int out_size, void* d_ws, size_t ws_size,
                              hipStream_t stream) {
    const float* x  = (const float*)d_in[0];
    const int*   ei = (const int*)d_in[1];
    const float* W0 = (const float*)d_in[2];  const float* b0 = (const float*)d_in[3];
    const float* W1 = (const float*)d_in[4];  const float* b1 = (const float*)d_in[5];
    const float* W2 = (const float*)d_in[6];  const float* b2 = (const float*)d_in[7];
    const float* Wq = (const float*)d_in[8];  const float* bq = (const float*)d_in[9];
    const float* Wk = (const float*)d_in[10]; const float* bk = (const float*)d_in[11];
    const float* Wv = (const float*)d_in[12]; const float* bv = (const float*)d_in[13];
    const float* Wo = (const float*)d_in[14]; const float* bo = (const float*)d_in[15];
    const float* g2 = (const float*)d_in[16]; const float* beta2 = (const float*)d_in[17];
    const float* Wm1 = (const float*)d_in[18]; const float* bm1 = (const float*)d_in[19];
    const float* Wm2 = (const float*)d_in[20]; const float* bm2 = (const float*)d_in[21];
    const float* Wl = (const float*)d_in[22]; const float* bl = (const float*)d_in[23];
    float* outp = (float*)d_out;

    const size_t BIG = (size_t)T_ * N_ * H_;
    char* ws = (char*)d_ws;
    float*    dinv = (float*)(ws);
    int*      ptr  = (int*)(ws + 640000);
    uint16_t* col  = (uint16_t*)(ws + 1280000);
    f16*      Wt   = (f16*)(ws + 6400000);
    f16*      P16  = (f16*)(ws + 6498304);
    f16*      Q16  = P16 + BIG;
    float*    z    = (float*)(Q16 + BIG);   // [0..4095] accum; [4096..4159] zerorow (row ZROW_ rel P16)
    float*    zq   = z + 4096 + 64;
    float*    zk   = zq + 4096;
    float*    zv   = zk + 4096;
    float*    xr   = zv + 4096;
    int*      part = (int*)P16;   // CSR partials alias P16 (used only before first gemm)
    float*    zpart = (float*)Q16; // aggr3 block partials alias Q16 (h2 dead after gemm3)

    k_wprep<<<3, 256, 0, stream>>>(W0, W1, W2, Wt);
    k_count<<<NB_ * 32, 256, 0, stream>>>(ei, part);
    k_scan<<<T_, 256, 0, stream>>>(part, ptr, dinv, z);
    k_scatter<<<NB_ * 32, 256, 0, stream>>>(ei, part, col);

    const int AGGR_BLOCKS = NBLK_ * 32;   // 16 nodes/block, 4 nodes/wave
    k_gemm<true><<<GEMMB, 256, 0, stream>>>(x, Wt, dinv, P16);
    k_aggr<<<AGGR_BLOCKS, 256, 0, stream>>>(ptr, col, P16, dinv, b0, Q16);
    k_gemm<false><<<GEMMB, 256, 0, stream>>>(Q16, Wt + 16384, dinv, P16);
    k_aggr<<<AGGR_BLOCKS, 256, 0, stream>>>(ptr, col, P16, dinv, b1, Q16);
    k_gemm<false><<<GEMMB, 256, 0, stream>>>(Q16, Wt + 32768, dinv, P16);
    // final layer: gather + per-block partial sums (no 40MB store, no 40MB re-read)
    k_aggr_red2<<<AGGR_BLOCKS, 256, 0, stream>>>(ptr, col, P16, dinv, b2, zpart);
    k_zred<<<T_, 128, 0, stream>>>(zpart, z);

    k_qkv<<<T_, 128, 0, stream>>>(z, Wq, bq, Wk, bk, Wv, bv, zq, zk, zv);
    k_attnmid<<<T_, 256, 0, stream>>>(zq, zk, zv, Wo, bo, g2, beta2,
                                      Wm1, bm1, Wm2, bm2, xr);
    k_final<<<1, 128, 0, stream>>>(xr, Wl, bl, outp);
}

// Round 14
// 489.201 us; speedup vs baseline: 2.7838x; 1.0132x over previous
//
#include <hip/hip_runtime.h>
#include <cstdint>

#define T_ 32
#define N_ 5000
#define E_ 80000
#define H_ 128
#define HD_ 512
#define C_ 10

typedef _Float16 f16;
typedef f16 f16x8 __attribute__((ext_vector_type(8)));
typedef f16 f16x4 __attribute__((ext_vector_type(4)));
typedef f16 f16x2 __attribute__((ext_vector_type(2)));
typedef float f32x4 __attribute__((ext_vector_type(4)));

#define LDA 136   // padded LDS leading dim in f16
#define NB_ 8     // CSR-build blocks per graph
#define EPS_ (E_ / NB_)  // 10000 edges per block
#define NBLK_ 313 // ceil(N_/16) 16-row blocks per graph (gemm tasks + aggr)
#define GEMMB 768 // gemm grid: 96 blocks/XCD * 8
#define ZROW_ 320064  // zero-row index rel. to P16: (2*BIG + 8192 f16)/128

__device__ inline float fast_tanh(float x) {
    return 1.0f - 2.0f / (__expf(2.0f * x) + 1.0f);
}

__device__ inline f16x8 cvt8(float4 a, float4 b) {
    return (f16x8){(f16)a.x, (f16)a.y, (f16)a.z, (f16)a.w,
                   (f16)b.x, (f16)b.y, (f16)b.z, (f16)b.w};
}

// ---------------- CSR build, LDS-atomic (no global atomics) ----------------
__global__ __launch_bounds__(256) void k_count(const int* __restrict__ ei, int* __restrict__ part) {
    __shared__ int cnt[N_];
    int blk = blockIdx.x;
    int t = blk & 31, seg = blk >> 5;
    int tid = threadIdx.x;
    for (int i = tid; i < N_; i += 256) cnt[i] = 0;
    __syncthreads();
    const int* dst = ei + (size_t)t * 2 * E_ + E_ + seg * EPS_;
    for (int e = tid * 4; e < EPS_; e += 1024) {
        int4 d = *(const int4*)&dst[e];
        atomicAdd(&cnt[d.x], 1);
        atomicAdd(&cnt[d.y], 1);
        atomicAdd(&cnt[d.z], 1);
        atomicAdd(&cnt[d.w], 1);
    }
    __syncthreads();
    int* p = part + (t * NB_ + seg) * N_;
    for (int i = tid * 4; i < N_; i += 1024) *(int4*)&p[i] = *(const int4*)&cnt[i];
}

// ---------------- scan v2: coalesced degree/fixup phases, LDS-staged scan ----------------
// Also zeroes z (node-sum accumulator) and the dedicated zerorow (gather
// redirect target; z+4096 floats; never written afterwards).
__global__ __launch_bounds__(256) void k_scan(int* __restrict__ part, int* __restrict__ ptr,
                                              float* __restrict__ dinv, float* __restrict__ z) {
    __shared__ int cnt[N_];      // degree, then start offset
    __shared__ int red[256];
    int t = blockIdx.x, tid = threadIdx.x;
    int base = t * N_;
    if (tid < 128) z[t * 128 + tid] = 0.0f;            // accumulator zero-init
    if (tid >= 128 && tid < 192) z[4096 + (tid - 128)] = 0.0f;  // zerorow (benign multi-block)
    int* pp = part + t * NB_ * N_;

    // Phase A: coalesced degree computation
    for (int i = tid; i < N_; i += 256) {
        int c = 0;
#pragma unroll
        for (int s = 0; s < NB_; ++s) c += pp[s * N_ + i];
        cnt[i] = c;
        dinv[base + i] = rsqrtf((float)(c + 1));  // +1 self-loop
    }
    __syncthreads();

    // Phase B: block scan over blocked 20-element runs (LDS source)
    int vals[20];
    int sum = 0;
#pragma unroll
    for (int j = 0; j < 20; ++j) {
        int i = tid * 20 + j;
        int c = (i < N_) ? cnt[i] : 0;
        vals[j] = sum;
        sum += c;
    }
    red[tid] = sum;
    __syncthreads();
    for (int off = 1; off < 256; off <<= 1) {
        int v = (tid >= off) ? red[tid - off] : 0;
        __syncthreads();
        red[tid] += v;
        __syncthreads();
    }
    int prev = (tid > 0) ? red[tid - 1] : 0;
#pragma unroll
    for (int j = 0; j < 20; ++j) {
        int i = tid * 20 + j;
        if (i < N_) cnt[i] = prev + vals[j];   // overwrite degree with start offset
    }
    __syncthreads();

    // Phase C: coalesced ptr write + per-segment running-offset fixup
    for (int i = tid; i < N_; i += 256) {
        int run = cnt[i];
        ptr[base + i] = run;
#pragma unroll
        for (int s = 0; s < NB_; ++s) {
            int c = pp[s * N_ + i];
            pp[s * N_ + i] = run;
            run += c;
        }
    }
}

__global__ __launch_bounds__(256) void k_scatter(const int* __restrict__ ei,
                                                 const int* __restrict__ part,
                                                 uint16_t* __restrict__ col) {
    __shared__ int cur[N_];
    int blk = blockIdx.x;
    int t = blk & 31, seg = blk >> 5;
    int tid = threadIdx.x;
    const int* off = part + (t * NB_ + seg) * N_;
    for (int i = tid * 4; i < N_; i += 1024) *(int4*)&cur[i] = *(const int4*)&off[i];
    __syncthreads();
    const int* src = ei + (size_t)t * 2 * E_ + seg * EPS_;
    const int* dst = src + E_;
    uint16_t* cl = col + (size_t)t * E_;
    for (int e = tid * 4; e < EPS_; e += 1024) {
        int4 s4 = *(const int4*)&src[e];
        int4 d4 = *(const int4*)&dst[e];
        cl[atomicAdd(&cur[d4.x], 1)] = (uint16_t)s4.x;
        cl[atomicAdd(&cur[d4.y], 1)] = (uint16_t)s4.y;
        cl[atomicAdd(&cur[d4.z], 1)] = (uint16_t)s4.z;
        cl[atomicAdd(&cur[d4.w], 1)] = (uint16_t)s4.w;
    }
}

// ---------------- weight prep: Wt[l][c][k] = (f16)W_l[k][c] ----------------
__global__ __launch_bounds__(256) void k_wprep(const float* __restrict__ W0,
                                               const float* __restrict__ W1,
                                               const float* __restrict__ W2,
                                               f16* __restrict__ Wt) {
    const float* W = (blockIdx.x == 0) ? W0 : (blockIdx.x == 1) ? W1 : W2;
    f16* dst = Wt + blockIdx.x * 16384;
    for (int idx = threadIdx.x; idx < 16384; idx += 256) {
        int c = idx >> 7, k = idx & 127;
        dst[idx] = (f16)W[k * 128 + c];
    }
}

// ---------------- MFMA GEMM v5: barrier-free streaming (measured keeper) ----------------
// K=128 fits one wave's MFMA fragments: no inter-wave A sharing. Stage Ws once ->
// ONE barrier -> waves grid-stride independent 16-row tasks; A direct global->reg;
// transpose via per-wave private LDS slab (lgkmcnt only); 1KB coalesced stores.
// Task order is graph-sequential in time (gsel 0 first): the SERPENTINE partner
// of the reversed-order aggr (consumer starts where producer ended, L2-warm).
template <bool F32IN>
__global__ __launch_bounds__(256, 3) void k_gemm(const void* __restrict__ in_,
                                                 const f16* __restrict__ Wt,  // [c][k]
                                                 const float* __restrict__ dinv,
                                                 f16* __restrict__ g) {
    __shared__ f16 Ws[128 * LDA];
    __shared__ f16 slab[4][16 * LDA];
    int tid = threadIdx.x;
    {
        int c = tid >> 1, hf = tid & 1;
        const f16* src = Wt + c * 128 + hf * 64;
        f16* dst = Ws + c * LDA + hf * 64;
#pragma unroll
        for (int j = 0; j < 8; ++j) *(f16x8*)&dst[j * 8] = *(const f16x8*)&src[j * 8];
    }
    __syncthreads();   // the ONLY barrier; waves run free below

    int xc = blockIdx.x & 7;
    int jb = blockIdx.x >> 3;            // 0..95 per XCD
    int w = tid >> 6, lane = tid & 63;
    int m = lane & 15, q = lane >> 4;
    int co = q * 8;
    f16* sl = slab[w];
    int srow = lane >> 4;                // store row-within-quad
    int scol = (lane & 15) * 8;          // store col

    for (int task = jb * 4 + w; task < 4 * NBLK_; task += 384) {
        int gsel = task / NBLK_;
        int tile = task - gsel * NBLK_;
        int t = xc + (gsel << 3);
        int base = t * N_;
        int r0 = tile * 16;
        int rowA = r0 + m; if (rowA >= N_) rowA = N_ - 1;   // clamp (not stored)

        // A fragments: direct global -> registers
        f16x8 a0, a1, a2, a3;
        if (F32IN) {
            const float* src = (const float*)in_ + (((size_t)(base + rowA)) << 7) + co;
            float4 u0 = *(const float4*)&src[0];
            float4 u1 = *(const float4*)&src[4];
            float4 u2 = *(const float4*)&src[32];
            float4 u3 = *(const float4*)&src[36];
            float4 u4 = *(const float4*)&src[64];
            float4 u5 = *(const float4*)&src[68];
            float4 u6 = *(const float4*)&src[96];
            float4 u7 = *(const float4*)&src[100];
            a0 = cvt8(u0, u1); a1 = cvt8(u2, u3); a2 = cvt8(u4, u5); a3 = cvt8(u6, u7);
        } else {
            const f16* src = (const f16*)in_ + (((size_t)(base + rowA)) << 7) + co;
            a0 = *(const f16x8*)&src[0];
            a1 = *(const f16x8*)&src[32];
            a2 = *(const f16x8*)&src[64];
            a3 = *(const f16x8*)&src[96];
        }

        f32x4 acc[8];
#pragma unroll
        for (int n = 0; n < 8; ++n) acc[n] = (f32x4){0.f, 0.f, 0.f, 0.f};
#pragma unroll
        for (int n = 0; n < 8; ++n) {
            f16x8 bF = *(const f16x8*)&Ws[(n * 16 + m) * LDA + co];
            acc[n] = __builtin_amdgcn_mfma_f32_16x16x32_f16(a0, bF, acc[n], 0, 0, 0);
        }
#pragma unroll
        for (int n = 0; n < 8; ++n) {
            f16x8 bF = *(const f16x8*)&Ws[(n * 16 + m) * LDA + 32 + co];
            acc[n] = __builtin_amdgcn_mfma_f32_16x16x32_f16(a1, bF, acc[n], 0, 0, 0);
        }
#pragma unroll
        for (int n = 0; n < 8; ++n) {
            f16x8 bF = *(const f16x8*)&Ws[(n * 16 + m) * LDA + 64 + co];
            acc[n] = __builtin_amdgcn_mfma_f32_16x16x32_f16(a2, bF, acc[n], 0, 0, 0);
        }
#pragma unroll
        for (int n = 0; n < 8; ++n) {
            f16x8 bF = *(const f16x8*)&Ws[(n * 16 + m) * LDA + 96 + co];
            acc[n] = __builtin_amdgcn_mfma_f32_16x16x32_f16(a3, bF, acc[n], 0, 0, 0);
        }

        // epilogue: dinv scale -> per-wave slab (transpose) -> coalesced store
#pragma unroll
        for (int i = 0; i < 4; ++i) {
            int rr = q * 4 + i;
            int gr = r0 + rr; if (gr >= N_) gr = N_ - 1;
            float d = dinv[base + gr];
#pragma unroll
            for (int n = 0; n < 8; ++n)
                sl[rr * LDA + n * 16 + m] = (f16)(acc[n][i] * d);
        }
        asm volatile("s_waitcnt lgkmcnt(0)" ::: "memory");  // wave-internal write->read fence
#pragma unroll
        for (int j4 = 0; j4 < 4; ++j4) {
            int row = j4 * 4 + srow;
            f16x8 v = *(const f16x8*)&sl[row * LDA + scol];
            if (r0 + row < N_)
                *(f16x8*)&g[(((size_t)(base + r0 + row)) << 7) + scol] = v;  // 1KB/wave contiguous
        }
    }
}

// ---------------- CSR gather v4 + SERPENTINE graph order (layers 1 & 2) ----------------
// 16 nodes/block, 4 nodes/wave, barrier-free; gather loop at the random-256B-row
// L2 floor (do not touch). NEW: graph order per XCD is REVERSED (gsel -> 3-gsel).
// The producer gemm processes graphs 0->3 in time, so at handoff the XCD L2
// holds graphs 3 (+2); starting the aggr there converts HBM re-fetches (FETCH
// was 23MB, ~900cy) into L2 hits (~200cy). aggr ends on graph 0, which the next
// (forward-order) gemm starts with -- serpentine at every handoff.
// Out-of-range lanes redirect via ONE cndmask to the dedicated zerorow
// (z+4096 floats; row ZROW_-5000t rel. to gg=P16; zeroed by k_scan).
__global__ __launch_bounds__(256) void k_aggr(const int* __restrict__ ptr,
                                              const uint16_t* __restrict__ col,
                                              const f16* __restrict__ g,
                                              const float* __restrict__ dinv,
                                              const float* __restrict__ b,
                                              f16* __restrict__ out) {
    int x = blockIdx.x & 7;
    int j = blockIdx.x >> 3;
    int gsel = 3 - j / NBLK_;          // REVERSED graph order (serpentine)
    int nb = j - (j / NBLK_) * NBLK_;
    int t = x + (gsel << 3);

    int w = threadIdx.x >> 6;
    int lane = threadIdx.x & 63;
    int q = lane >> 4, m = lane & 15;
    int n0 = nb * 16 + w * 4;    // wave's first node (4-aligned)
    if (n0 >= N_) return;        // tail waves (no barriers in this kernel)
    int base = t * N_;
    const f16* gg = g + (size_t)base * H_;
    const uint16_t* cl = col + (size_t)t * E_;
    int n = n0 + q;              // this 16-lane group's node
    unsigned moB = (unsigned)(m * 8);   // lane's 8-col slice (element offset)

    int4 p4 = *(const int4*)&ptr[base + n0];
    int pend = (n0 + 4 < N_) ? ptr[base + n0 + 4] : E_;
    int begin = (q == 0) ? p4.x : (q == 1) ? p4.y : (q == 2) ? p4.z : p4.w;
    int end   = (q == 0) ? p4.y : (q == 1) ? p4.z : (q == 2) ? p4.w : pend;

    float dn = dinv[base + n];
    float4 b4a = *(const float4*)&b[m * 8];
    float4 b4b = *(const float4*)&b[m * 8 + 4];

    int zidx = ZROW_ - 5000 * t;

    f16x8 a0 = *(const f16x8*)&gg[((unsigned)n << 7) + moB];  // self-loop row
    f16x8 a1 = {}, a2 = {}, a3 = {}, a4 = {}, a5 = {}, a6 = {}, a7 = {};

    int e0 = begin & ~7;
    int elast = (end - 1) & ~7;
    unsigned span = (unsigned)(end - begin);
    uint4 cc = *(const uint4*)&cl[e0];
    for (int e = e0; e < end; e += 8) {
        int en = e + 8;
        int epf = en < elast ? en : elast;
        uint4 cn = *(const uint4*)&cl[epf];
        unsigned eb = (unsigned)(e - begin);
        int i0 = (int)(cc.x & 0xFFFFu), i1 = (int)(cc.x >> 16);
        int i2 = (int)(cc.y & 0xFFFFu), i3 = (int)(cc.y >> 16);
        int i4 = (int)(cc.z & 0xFFFFu), i5 = (int)(cc.z >> 16);
        int i6 = (int)(cc.w & 0xFFFFu), i7 = (int)(cc.w >> 16);
        int s0 = (eb + 0 < span) ? i0 : zidx;
        int s1 = (eb + 1 < span) ? i1 : zidx;
        int s2 = (eb + 2 < span) ? i2 : zidx;
        int s3 = (eb + 3 < span) ? i3 : zidx;
        int s4 = (eb + 4 < span) ? i4 : zidx;
        int s5 = (eb + 5 < span) ? i5 : zidx;
        int s6 = (eb + 6 < span) ? i6 : zidx;
        int s7 = (eb + 7 < span) ? i7 : zidx;
        f16x8 v0 = *(const f16x8*)&gg[((unsigned)s0 << 7) + moB];
        f16x8 v1 = *(const f16x8*)&gg[((unsigned)s1 << 7) + moB];
        f16x8 v2 = *(const f16x8*)&gg[((unsigned)s2 << 7) + moB];
        f16x8 v3 = *(const f16x8*)&gg[((unsigned)s3 << 7) + moB];
        f16x8 v4 = *(const f16x8*)&gg[((unsigned)s4 << 7) + moB];
        f16x8 v5 = *(const f16x8*)&gg[((unsigned)s5 << 7) + moB];
        f16x8 v6 = *(const f16x8*)&gg[((unsigned)s6 << 7) + moB];
        f16x8 v7 = *(const f16x8*)&gg[((unsigned)s7 << 7) + moB];
        a0 += v0; a1 += v1; a2 += v2; a3 += v3;
        a4 += v4; a5 += v5; a6 += v6; a7 += v7;
        cc = cn;
    }
    a0 += a1; a2 += a3; a4 += a5; a6 += a7;
    a0 += a2; a4 += a6;
    a0 += a4;

    f16x8 o;
#pragma unroll
    for (int jj = 0; jj < 8; ++jj) {
        float bj = (jj < 4) ? ((const float*)&b4a)[jj] : ((const float*)&b4b)[jj - 4];
        o[jj] = (f16)fast_tanh(dn * (float)a0[jj] + bj);
    }
    *(f16x8*)&out[((size_t)base + n) * H_ + moB] = o;  // contiguous 1 KB wave store
}

// ---------------- CSR gather + per-BLOCK partial sum (final layer) ----------------
// Same v4 gather (serpentine-reversed graph order like k_aggr); per-block
// 128-col partials via shfl + ONE end barrier + plain stores (no atomics --
// v11's per-wave atomics serialized 1250-deep/address). k_zred sums the 313
// partials per (t,c). Saves aggr3's 40MB write + k_reduce's 40MB read.
__global__ __launch_bounds__(256) void k_aggr_red2(const int* __restrict__ ptr,
                                                   const uint16_t* __restrict__ col,
                                                   const f16* __restrict__ g,
                                                   const float* __restrict__ dinv,
                                                   const float* __restrict__ b,
                                                   float* __restrict__ partial) {
    __shared__ float sh[4][128];
    int x = blockIdx.x & 7;
    int j = blockIdx.x >> 3;
    int gsel = 3 - j / NBLK_;          // REVERSED graph order (serpentine)
    int nb = j - (j / NBLK_) * NBLK_;
    int t = x + (gsel << 3);

    int tid = threadIdx.x;
    int w = tid >> 6;
    int lane = tid & 63;
    int q = lane >> 4, m = lane & 15;
    int n0 = nb * 16 + w * 4;
    bool wvalid = n0 < N_;       // tail waves still reach the barrier
    int base = t * N_;
    const f16* gg = g + (size_t)base * H_;
    const uint16_t* cl = col + (size_t)t * E_;
    int n = wvalid ? (n0 + q) : (N_ - 1);   // safe address; contribution zeroed below
    unsigned moB = (unsigned)(m * 8);

    int begin = 0, end = 0;
    float dn = 0.0f;
    if (wvalid) {
        int4 p4 = *(const int4*)&ptr[base + n0];
        int pend = (n0 + 4 < N_) ? ptr[base + n0 + 4] : E_;
        begin = (q == 0) ? p4.x : (q == 1) ? p4.y : (q == 2) ? p4.z : p4.w;
        end   = (q == 0) ? p4.y : (q == 1) ? p4.z : (q == 2) ? p4.w : pend;
        dn = dinv[base + n];
    }
    float4 b4a = *(const float4*)&b[m * 8];
    float4 b4b = *(const float4*)&b[m * 8 + 4];
    int zidx = ZROW_ - 5000 * t;

    f16x8 a0 = {};
    if (wvalid) a0 = *(const f16x8*)&gg[((unsigned)n << 7) + moB];  // self-loop row
    f16x8 a1 = {}, a2 = {}, a3 = {}, a4 = {}, a5 = {}, a6 = {}, a7 = {};

    if (wvalid && begin < end) {
        int e0 = begin & ~7;
        int elast = (end - 1) & ~7;
        unsigned span = (unsigned)(end - begin);
        uint4 cc = *(const uint4*)&cl[e0];
        for (int e = e0; e < end; e += 8) {
            int en = e + 8;
            int epf = en < elast ? en : elast;
            uint4 cn = *(const uint4*)&cl[epf];
            unsigned eb = (unsigned)(e - begin);
            int i0 = (int)(cc.x & 0xFFFFu), i1 = (int)(cc.x >> 16);
            int i2 = (int)(cc.y & 0xFFFFu), i3 = (int)(cc.y >> 16);
            int i4 = (int)(cc.z & 0xFFFFu), i5 = (int)(cc.z >> 16);
            int i6 = (int)(cc.w & 0xFFFFu), i7 = (int)(cc.w >> 16);
            int s0 = (eb + 0 < span) ? i0 : zidx;
            int s1 = (eb + 1 < span) ? i1 : zidx;
            int s2 = (eb + 2 < span) ? i2 : zidx;
            int s3 = (eb + 3 < span) ? i3 : zidx;
            int s4 = (eb + 4 < span) ? i4 : zidx;
            int s5 = (eb + 5 < span) ? i5 : zidx;
            int s6 = (eb + 6 < span) ? i6 : zidx;
            int s7 = (eb + 7 < span) ? i7 : zidx;
            f16x8 v0 = *(const f16x8*)&gg[((unsigned)s0 << 7) + moB];
            f16x8 v1 = *(const f16x8*)&gg[((unsigned)s1 << 7) + moB];
            f16x8 v2 = *(const f16x8*)&gg[((unsigned)s2 << 7) + moB];
            f16x8 v3 = *(const f16x8*)&gg[((unsigned)s3 << 7) + moB];
            f16x8 v4 = *(const f16x8*)&gg[((unsigned)s4 << 7) + moB];
            f16x8 v5 = *(const f16x8*)&gg[((unsigned)s5 << 7) + moB];
            f16x8 v6 = *(const f16x8*)&gg[((unsigned)s6 << 7) + moB];
            f16x8 v7 = *(const f16x8*)&gg[((unsigned)s7 << 7) + moB];
            a0 += v0; a1 += v1; a2 += v2; a3 += v3;
            a4 += v4; a5 += v5; a6 += v6; a7 += v7;
            cc = cn;
        }
    }
    a0 += a1; a2 += a3; a4 += a5; a6 += a7;
    a0 += a2; a4 += a6;
    a0 += a4;

    // tanh (f16-rounded to match stored-value semantics), zeroed for tail waves
    float s0_ = 0.f, s1_ = 0.f, s2_ = 0.f, s3_ = 0.f, s4_ = 0.f, s5_ = 0.f, s6_ = 0.f, s7_ = 0.f;
    if (wvalid) {
        s0_ = (float)(f16)fast_tanh(dn * (float)a0[0] + ((const float*)&b4a)[0]);
        s1_ = (float)(f16)fast_tanh(dn * (float)a0[1] + ((const float*)&b4a)[1]);
        s2_ = (float)(f16)fast_tanh(dn * (float)a0[2] + ((const float*)&b4a)[2]);
        s3_ = (float)(f16)fast_tanh(dn * (float)a0[3] + ((const float*)&b4a)[3]);
        s4_ = (float)(f16)fast_tanh(dn * (float)a0[4] + ((const float*)&b4b)[0]);
        s5_ = (float)(f16)fast_tanh(dn * (float)a0[5] + ((const float*)&b4b)[1]);
        s6_ = (float)(f16)fast_tanh(dn * (float)a0[6] + ((const float*)&b4b)[2]);
        s7_ = (float)(f16)fast_tanh(dn * (float)a0[7] + ((const float*)&b4b)[3]);
    }
    // sum across the wave's 4 nodes (lanes differ only in q for fixed m)
    s0_ += __shfl_xor(s0_, 16, 64); s0_ += __shfl_xor(s0_, 32, 64);
    s1_ += __shfl_xor(s1_, 16, 64); s1_ += __shfl_xor(s1_, 32, 64);
    s2_ += __shfl_xor(s2_, 16, 64); s2_ += __shfl_xor(s2_, 32, 64);
    s3_ += __shfl_xor(s3_, 16, 64); s3_ += __shfl_xor(s3_, 32, 64);
    s4_ += __shfl_xor(s4_, 16, 64); s4_ += __shfl_xor(s4_, 32, 64);
    s5_ += __shfl_xor(s5_, 16, 64); s5_ += __shfl_xor(s5_, 32, 64);
    s6_ += __shfl_xor(s6_, 16, 64); s6_ += __shfl_xor(s6_, 32, 64);
    s7_ += __shfl_xor(s7_, 16, 64); s7_ += __shfl_xor(s7_, 32, 64);
    if (q == 0) {
        float* sp = &sh[w][m * 8];
        sp[0] = s0_; sp[1] = s1_; sp[2] = s2_; sp[3] = s3_;
        sp[4] = s4_; sp[5] = s5_; sp[6] = s6_; sp[7] = s7_;
    }
    __syncthreads();   // only barrier; post-barrier work is ~10 instructions
    if (tid < 128) {
        float s = sh[0][tid] + sh[1][tid] + sh[2][tid] + sh[3][tid];
        partial[((size_t)(t * NBLK_ + nb)) * 128 + tid] = s;   // coalesced, no atomics
    }
}

// ---------------- z reduction: z[t][c] = sum over 313 block partials ----------------
__global__ __launch_bounds__(128) void k_zred(const float* __restrict__ partial,
                                              float* __restrict__ z) {
    int t = blockIdx.x, c = threadIdx.x;
    const float* p = partial + (size_t)t * NBLK_ * 128 + c;
    float s = 0.0f;
    for (int nb = 0; nb < NBLK_; ++nb) s += p[nb * 128];
    z[t * 128 + c] = s;
}

// ---------------- head stage 1: q,k,v ----------------
__global__ __launch_bounds__(128) void k_qkv(const float* __restrict__ z,
                                             const float* __restrict__ Wq, const float* __restrict__ bq,
                                             const float* __restrict__ Wk, const float* __restrict__ bk,
                                             const float* __restrict__ Wv, const float* __restrict__ bv,
                                             float* __restrict__ q, float* __restrict__ k,
                                             float* __restrict__ v) {
    int t = blockIdx.x, c = threadIdx.x;
    __shared__ float zs[128];
    zs[c] = z[t * 128 + c];
    __syncthreads();
    float aq = bq[c], ak = bk[c], av = bv[c];
    for (int kk = 0; kk < 128; ++kk) {
        float zv = zs[kk];
        aq += zv * Wq[(kk << 7) + c];
        ak += zv * Wk[(kk << 7) + c];
        av += zv * Wv[(kk << 7) + c];
    }
    q[t * 128 + c] = aq;
    k[t * 128 + c] = ak;
    v[t * 128 + c] = av;
}

// ---------------- head stage 2 ----------------
__global__ __launch_bounds__(256) void k_attnmid(
    const float* __restrict__ q, const float* __restrict__ k, const float* __restrict__ v,
    const float* __restrict__ Wo, const float* __restrict__ bo,
    const float* __restrict__ g2, const float* __restrict__ beta2,
    const float* __restrict__ Wm1, const float* __restrict__ bm1,
    const float* __restrict__ Wm2, const float* __restrict__ bm2,
    float* __restrict__ xr) {
    int t = blockIdx.x, tid = threadIdx.x;
    __shared__ float Ks[32 * 128], Vs[32 * 128];
    __shared__ float qs[128], sc[8 * 32], xa[128], hid[512], ys[128];
    __shared__ float redA[128], redB[128];

    for (int i = tid; i < 32 * 128; i += 256) { Ks[i] = k[i]; Vs[i] = v[i]; }
    if (tid < 128) qs[tid] = q[t * 128 + tid];
    __syncthreads();

    {
        int h = tid >> 5, s = tid & 31;
        float d = 0.0f;
#pragma unroll
        for (int kk = 0; kk < 16; ++kk)
            d += qs[(h << 4) + kk] * Ks[(s << 7) + (h << 4) + kk];
        sc[tid] = d * 0.25f;
    }
    __syncthreads();
    if (tid < 8) {
        float m = -1e30f;
        for (int s = 0; s < 32; ++s) m = fmaxf(m, sc[(tid << 5) + s]);
        float l = 0.0f;
        for (int s = 0; s < 32; ++s) { float e = __expf(sc[(tid << 5) + s] - m); sc[(tid << 5) + s] = e; l += e; }
        float inv = 1.0f / l;
        for (int s = 0; s < 32; ++s) sc[(tid << 5) + s] *= inv;
    }
    __syncthreads();
    if (tid < 128) {
        int h = tid >> 4;
        float o = 0.0f;
        for (int s = 0; s < 32; ++s) o += sc[(h << 5) + s] * Vs[(s << 7) + tid];
        qs[tid] = o;
    }
    __syncthreads();
    if (tid < 128) {
        float a = bo[tid];
        for (int kk = 0; kk < 128; ++kk) a += qs[kk] * Wo[(kk << 7) + tid];
        xa[tid] = a;
    }
    __syncthreads();
    for (int j = tid; j < 512; j += 256) {
        float a = bm1[j];
        for (int kk = 0; kk < 128; ++kk) a += xa[kk] * Wm1[(kk << 9) + j];
        hid[j] = fmaxf(a, 0.0f);
    }
    __syncthreads();
    if (tid < 128) {
        float a = bm2[tid];
        for (int j = 0; j < 512; ++j) a += hid[j] * Wm2[(j << 7) + tid];
        ys[tid] = xa[tid] + a;
    }
    __syncthreads();
    if (tid < 128) { redA[tid] = ys[tid]; redB[tid] = ys[tid] * ys[tid]; }
    __syncthreads();
    for (int off = 64; off > 0; off >>= 1) {
        if (tid < off) { redA[tid] += redA[tid + off]; redB[tid] += redB[tid + off]; }
        __syncthreads();
    }
    float mu = redA[0] * (1.0f / 128.0f);
    float var = redB[0] * (1.0f / 128.0f) - mu * mu;
    float rs = rsqrtf(var + 1e-5f);
    if (tid < 128) {
        float yv = (ys[tid] - mu) * rs * g2[tid] + beta2[tid];
        xr[t * 128 + tid] = fmaxf(yv, 0.0f);
    }
}

// ---------------- head stage 3 ----------------
__global__ __launch_bounds__(128) void k_final(const float* __restrict__ xr,
                                               const float* __restrict__ Wl,
                                               const float* __restrict__ bl,
                                               float* __restrict__ out) {
    int tid = threadIdx.x;
    __shared__ float pooled[128];
    float s = 0.0f;
    for (int t = 0; t < 32; ++t) s += xr[t * 128 + tid];
    pooled[tid] = s;
    __syncthreads();
    if (tid < C_) {
        float a = bl[tid];
        for (int kk = 0; kk < 128; ++kk) a += pooled[kk] * Wl[kk * C_ + tid];
        out[tid] = a;
    }
}

extern "C" void kernel_launch(void* const* d_in, const int* in_sizes, int n_in,
                              void* d_out, int out_size, void* d_ws, size_t ws_size,
                              hipStream_t stream) {
    const float* x  = (const float*)d_in[0];
    const int*   ei = (const int*)d_in[1];
    const float* W0 = (const float*)d_in[2];  const float* b0 = (const float*)d_in[3];
    const float* W1 = (const float*)d_in[4];  const float* b1 = (const float*)d_in[5];
    const float* W2 = (const float*)d_in[6];  const float* b2 = (const float*)d_in[7];
    const float* Wq = (const float*)d_in[8];  const float* bq = (const float*)d_in[9];
    const float* Wk = (const float*)d_in[10]; const float* bk = (const float*)d_in[11];
    const float* Wv = (const float*)d_in[12]; const float* bv = (const float*)d_in[13];
    const float* Wo = (const float*)d_in[14]; const float* bo = (const float*)d_in[15];
    const float* g2 = (const float*)d_in[16]; const float* beta2 = (const float*)d_in[17];
    const float* Wm1 = (const float*)d_in[18]; const float* bm1 = (const float*)d_in[19];
    const float* Wm2 = (const float*)d_in[20]; const float* bm2 = (const float*)d_in[21];
    const float* Wl = (const float*)d_in[22]; const float* bl = (const float*)d_in[23];
    float* outp = (float*)d_out;

    const size_t BIG = (size_t)T_ * N_ * H_;
    char* ws = (char*)d_ws;
    float*    dinv = (float*)(ws);
    int*      ptr  = (int*)(ws + 640000);
    uint16_t* col  = (uint16_t*)(ws + 1280000);
    f16*      Wt   = (f16*)(ws + 6400000);
    f16*      P16  = (f16*)(ws + 6498304);
    f16*      Q16  = P16 + BIG;
    float*    z    = (float*)(Q16 + BIG);   // [0..4095] accum; [4096..4159] zerorow (row ZROW_ rel P16)
    float*    zq   = z + 4096 + 64;
    float*    zk   = zq + 4096;
    float*    zv   = zk + 4096;
    float*    xr   = zv + 4096;
    int*      part = (int*)P16;   // CSR partials alias P16 (used only before first gemm)
    float*    zpart = (float*)Q16; // aggr3 block partials alias Q16 (h2 dead after gemm3)

    k_wprep<<<3, 256, 0, stream>>>(W0, W1, W2, Wt);
    k_count<<<NB_ * 32, 256, 0, stream>>>(ei, part);
    k_scan<<<T_, 256, 0, stream>>>(part, ptr, dinv, z);
    k_scatter<<<NB_ * 32, 256, 0, stream>>>(ei, part, col);

    const int AGGR_BLOCKS = NBLK_ * 32;   // 16 nodes/block, 4 nodes/wave
    k_gemm<true><<<GEMMB, 256, 0, stream>>>(x, Wt, dinv, P16);
    k_aggr<<<AGGR_BLOCKS, 256, 0, stream>>>(ptr, col, P16, dinv, b0, Q16);
    k_gemm<false><<<GEMMB, 256, 0, stream>>>(Q16, Wt + 16384, dinv, P16);
    k_aggr<<<AGGR_BLOCKS, 256, 0, stream>>>(ptr, col, P16, dinv, b1, Q16);
    k_gemm<false><<<GEMMB, 256, 0, stream>>>(Q16, Wt + 32768, dinv, P16);
    // final layer: gather + per-block partial sums (no 40MB store, no 40MB re-read)
    k_aggr_red2<<<AGGR_BLOCKS, 256, 0, stream>>>(ptr, col, P16, dinv, b2, zpart);
    k_zred<<<T_, 128, 0, stream>>>(zpart, z);

    k_qkv<<<T_, 128, 0, stream>>>(z, Wq, bq, Wk, bk, Wv, bv, zq, zk, zv);
    k_attnmid<<<T_, 256, 0, stream>>>(zq, zk, zv, Wo, bo, g2, beta2,
                                      Wm1, bm1, Wm2, bm2, xr);
    k_final<<<1, 128, 0, stream>>>(xr, Wl, bl, outp);
}